// Round 10
// baseline (1029.677 us; speedup 1.0000x reference)
//
#include <hip/hip_runtime.h>
#include <hip/hip_bf16.h>
#include <cmath>
#include <cstddef>

#define THREADS 256
typedef unsigned short u16;
typedef unsigned int u32;
typedef __attribute__((ext_vector_type(8))) short bf16x8;
typedef __attribute__((ext_vector_type(4))) float f32x4;
#define MFMA16(a, b, c) __builtin_amdgcn_mfma_f32_16x16x32_bf16(a, b, c, 0, 0, 0)

__device__ __forceinline__ float bf2f(u16 u) {
  union { u32 i; float f; } x; x.i = ((u32)u) << 16; return x.f;
}
// native bf16 conversion (compiler emits v_cvt_pk_bf16_f32 for pairs)
__device__ __forceinline__ u16 f2bf(float f) {
  __hip_bfloat16 h = __float2bfloat16(f);
  return *reinterpret_cast<u16*>(&h);
}
__device__ __forceinline__ u32 f2bf2(float a, float b) {
  __hip_bfloat162 h = __float22bfloat162_rn(make_float2(a, b));
  return *reinterpret_cast<u32*>(&h);
}

// async global->LDS, 16B per lane; LDS dest is wave-uniform base + lane*16
__device__ __forceinline__ void gload16(const u16* g, u16* l) {
  __builtin_amdgcn_global_load_lds(
      (const __attribute__((address_space(1))) unsigned int*)g,
      (__attribute__((address_space(3))) unsigned int*)l, 16, 0, 0);
}

__device__ __forceinline__ float block_reduce_sum256(float v, float* red4) {
  for (int off = 32; off > 0; off >>= 1) v += __shfl_down(v, off);
  __syncthreads();
  if ((threadIdx.x & 63) == 0) red4[threadIdx.x >> 6] = v;
  __syncthreads();
  return red4[0] + red4[1] + red4[2] + red4[3];
}

// ---------------------------------------------------------------------------
__global__ void f2b_kernel(const float* __restrict__ in, u16* __restrict__ out,
                           int n) {
  int i = (blockIdx.x * THREADS + threadIdx.x) * 4;
  if (i >= n) return;
  float4 v = *reinterpret_cast<const float4*>(in + i);
  ushort4 o;
  o.x = f2bf(v.x); o.y = f2bf(v.y); o.z = f2bf(v.z); o.w = f2bf(v.w);
  *reinterpret_cast<ushort4*>(out + i) = o;
}

// neck conv2 weight: src OIHW [256][256][3][3] -> dst [o][(ky*3+kx)*256 + c]
__global__ void neck2w_kernel(const float* __restrict__ src,
                              u16* __restrict__ dst) {
  int idx = blockIdx.x * THREADS + threadIdx.x;
  if (idx >= 256 * 2304) return;
  int o = idx / 2304, r = idx % 2304;
  int n9 = r >> 8, c = r & 255;
  dst[idx] = f2bf(src[(size_t)(o * 256 + c) * 9 + n9]);
}

// ---------------------------------------------------------------------------
__global__ void im2col_patch_kernel(const float* __restrict__ img,
                                    u16* __restrict__ out) {
  int idx = blockIdx.x * THREADS + threadIdx.x;
  if (idx >= 4096 * 768) return;
  int col = idx % 768, tok = idx / 768;
  int ph = tok / 64, pw = tok % 64;
  int c = col / 256, r = col % 256;
  int i = r / 16, j = r % 16;
  out[idx] = f2bf(img[(size_t)(c * 1024 + ph * 16 + i) * 1024 + pw * 16 + j]);
}

// ---------------------------------------------------------------------------
// MFMA GEMM: C[M,N] = A[M,K]bf16 @ B[N,K]bf16^T, fp32 accum.
// 128xBN tile (BN=128 or 64), BK=64, 4 waves. Staging via global_load_lds
// with source-side inverse XOR swizzle (slot c' holds chunk c'^(row&7)).
// MODE 0: f32 out (+bias)(+res); 1: GELU->bf16; 2: bf16, q-cols x0.125;
// MODE 3: f32 out + bf16 mirror out2.
// ---------------------------------------------------------------------------
template <int MODE, int BN>
__global__ __launch_bounds__(256)
void gemm_bf16(const u16* __restrict__ A, const u16* __restrict__ B,
               const float* __restrict__ bias, const float* __restrict__ res,
               void* __restrict__ out, void* __restrict__ out2,
               int M, int N, int K) {
  constexpr int NF = BN / 32;  // per-wave n fragments
  __shared__ __attribute__((aligned(16))) u16 As[128 * 64];
  __shared__ __attribute__((aligned(16))) u16 Bs[BN * 64];
  const int t = threadIdx.x;
  const int w = t >> 6, l = t & 63;
  const int m0 = blockIdx.y * 128, n0 = blockIdx.x * BN;
  const int wm = (w >> 1) * 64, wn = (w & 1) * (BN / 2);
  f32x4 acc[4][NF];
#pragma unroll
  for (int i = 0; i < 4; ++i)
#pragma unroll
    for (int j = 0; j < NF; ++j) acc[i][j] = (f32x4){0.f, 0.f, 0.f, 0.f};

  // staging source addresses (inverse-swizzled chunk per lane)
  const int rr = l >> 3;                 // row-in-8 group
  const int cc = ((l & 7) ^ rr) * 8;     // source chunk offset (u16)
  const u16* aP[4];
  const u16* bP[NF];
#pragma unroll
  for (int j = 0; j < 4; ++j) {
    int ar = m0 + w * 32 + j * 8 + rr;
    if (ar >= M) ar = M - 1;
    aP[j] = A + (size_t)ar * K + cc;
  }
#pragma unroll
  for (int j = 0; j < NF; ++j)
    bP[j] = B + (size_t)(n0 + w * (BN / 4) + j * 8 + rr) * K + cc;
  u16* asw = &As[w * 2048];
  u16* bsw = &Bs[w * (BN * 16)];

  for (int k0 = 0; k0 < K; k0 += 64) {
    __syncthreads();
#pragma unroll
    for (int j = 0; j < 4; ++j) gload16(aP[j] + k0, asw + j * 512);
#pragma unroll
    for (int j = 0; j < NF; ++j) gload16(bP[j] + k0, bsw + j * 512);
    asm volatile("s_waitcnt vmcnt(0)" ::: "memory");
    __syncthreads();
#pragma unroll
    for (int kc = 0; kc < 2; ++kc) {
      bf16x8 af[4], bf[NF];
#pragma unroll
      for (int i = 0; i < 4; ++i) {
        int ar = wm + i * 16 + (l & 15);
        int ac = (kc * 4 + (l >> 4)) ^ (ar & 7);
        af[i] = *reinterpret_cast<const bf16x8*>(&As[ar * 64 + ac * 8]);
      }
#pragma unroll
      for (int j = 0; j < NF; ++j) {
        int br = wn + j * 16 + (l & 15);
        int bc = (kc * 4 + (l >> 4)) ^ (br & 7);
        bf[j] = *reinterpret_cast<const bf16x8*>(&Bs[br * 64 + bc * 8]);
      }
#pragma unroll
      for (int i = 0; i < 4; ++i)
#pragma unroll
        for (int j = 0; j < NF; ++j)
          acc[i][j] = MFMA16(af[i], bf[j], acc[i][j]);
    }
  }

#pragma unroll
  for (int i = 0; i < 4; ++i) {
#pragma unroll
    for (int reg = 0; reg < 4; ++reg) {
      int m = m0 + wm + i * 16 + (l >> 4) * 4 + reg;
      if (m >= M) continue;
#pragma unroll
      for (int j = 0; j < NF; ++j) {
        int n = n0 + wn + j * 16 + (l & 15);
        float v = acc[i][j][reg];
        if (bias) v += bias[n];
        if (MODE == 0 || MODE == 3) {
          if (res) v += res[(size_t)m * N + n];
          ((float*)out)[(size_t)m * N + n] = v;
          if (MODE == 3) ((u16*)out2)[(size_t)m * N + n] = f2bf(v);
        } else if (MODE == 1) {
          v = 0.5f * v * (1.0f + erff(v * 0.70710678118654752f));
          ((u16*)out)[(size_t)m * N + n] = f2bf(v);
        } else {  // MODE 2
          float sc = (n < 768) ? 0.125f : 1.0f;
          ((u16*)out)[(size_t)m * N + n] = f2bf(v * sc);
        }
      }
    }
  }
}

// ---------------------------------------------------------------------------
// relpos as batched 64x64x64 MFMA GEMM (S=64 only).
// WHICH=0 (rel_h): fixed qh -> C[qw][k] = Q[qh,qw,:]·Rh[qh-k+63,:]^T
// WHICH=1 (rel_w): fixed qw -> C[qh][k] = Q[qh,qw,:]·Rw[qw-k+63,:]^T
// ---------------------------------------------------------------------------
template <int WHICH>
__global__ __launch_bounds__(256)
void relpos_mfma_kernel(const u16* __restrict__ qkvb,
                        const u16* __restrict__ Rtab,
                        u16* __restrict__ relout) {
  __shared__ __attribute__((aligned(16))) u16 Ql[64 * 64];
  __shared__ __attribute__((aligned(16))) u16 Rl[64 * 64];
  const int t = threadIdx.x, w = t >> 6, l = t & 63;
  const int head = blockIdx.x >> 6;
  const int fixed = blockIdx.x & 63;  // qh (WHICH=0) or qw (WHICH=1)
  const int rr = l >> 3;
  const int cc = ((l & 7) ^ rr) * 8;  // inverse-swizzled source chunk

#pragma unroll
  for (int j = 0; j < 2; ++j) {
    int row = w * 16 + j * 8 + rr;
    int tok = (WHICH == 0) ? (fixed * 64 + row) : (row * 64 + fixed);
    gload16(qkvb + (size_t)tok * 2304 + head * 64 + cc, &Ql[w * 1024 + j * 512]);
    int rrow = fixed - row + 63;  // always in [0,126]
    gload16(Rtab + rrow * 64 + cc, &Rl[w * 1024 + j * 512]);
  }
  asm volatile("s_waitcnt vmcnt(0)" ::: "memory");
  __syncthreads();

  f32x4 acc[4];
#pragma unroll
  for (int j = 0; j < 4; ++j) acc[j] = (f32x4){0.f, 0.f, 0.f, 0.f};
#pragma unroll
  for (int kc = 0; kc < 2; ++kc) {
    int ar = w * 16 + (l & 15);
    int ac = (kc * 4 + (l >> 4)) ^ (ar & 7);
    bf16x8 af = *reinterpret_cast<const bf16x8*>(&Ql[ar * 64 + ac * 8]);
#pragma unroll
    for (int j = 0; j < 4; ++j) {
      int br = j * 16 + (l & 15);
      int bc = (kc * 4 + (l >> 4)) ^ (br & 7);
      bf16x8 bf = *reinterpret_cast<const bf16x8*>(&Rl[br * 64 + bc * 8]);
      acc[j] = MFMA16(af, bf, acc[j]);
    }
  }

#pragma unroll
  for (int j = 0; j < 4; ++j) {
#pragma unroll
    for (int reg = 0; reg < 4; ++reg) {
      int m = w * 16 + (l >> 4) * 4 + reg;  // qw (WHICH=0) / qh (WHICH=1)
      int n = j * 16 + (l & 15);            // k
      size_t o = (WHICH == 0)
                     ? ((((size_t)head * 64 + fixed) * 64 + m) * 64 + n)
                     : ((((size_t)head * 64 + m) * 64 + fixed) * 64 + n);
      relout[o] = f2bf(acc[j][reg] * 8.0f);
    }
  }
}

// ---------------------------------------------------------------------------
__global__ void ln_row_kernel(const float* __restrict__ in,
                              const float* __restrict__ w,
                              const float* __restrict__ b,
                              u16* __restrict__ out, int D) {
  __shared__ float red[4];
  size_t base = (size_t)blockIdx.x * D;
  float s = 0.f, s2 = 0.f;
  for (int i = threadIdx.x; i < D; i += THREADS) {
    float v = in[base + i];
    s += v; s2 += v * v;
  }
  s = block_reduce_sum256(s, red);
  s2 = block_reduce_sum256(s2, red);
  float m = s / (float)D;
  float var = s2 / (float)D - m * m;
  float inv = rsqrtf(var + 1e-6f);
  for (int i = threadIdx.x; i < D; i += THREADS) {
    float v = in[base + i];
    out[base + i] = f2bf((v - m) * inv * w[i] + b[i]);
  }
}

// ---------------------------------------------------------------------------
__global__ void win_part_kernel(const u16* __restrict__ h,
                                u16* __restrict__ out) {
  int idx = blockIdx.x * THREADS + threadIdx.x;
  if (idx >= 4900 * 768) return;
  int c = idx % 768;
  int tok = idx / 768;
  int win = tok / 196, r = tok % 196;
  int wy = r / 14, wx = r % 14;
  int gy = (win / 5) * 14 + wy;
  int gx = (win % 5) * 14 + wx;
  out[idx] = (gy < 64 && gx < 64) ? h[((size_t)gy * 64 + gx) * 768 + c] : (u16)0;
}

__global__ void win_unpart_add_kernel(const float* __restrict__ p,
                                      float* __restrict__ x) {
  int idx = blockIdx.x * THREADS + threadIdx.x;
  if (idx >= 4096 * 768) return;
  int c = idx % 768;
  int tok = idx / 768;
  int gy = tok / 64, gx = tok % 64;
  int win = (gy / 14) * 5 + (gx / 14);
  int wy = gy % 14, wx = gx % 14;
  x[idx] += p[((size_t)(win * 196 + wy * 14 + wx)) * 768 + c];
}

__global__ void add_kernel(const float* __restrict__ p, float* __restrict__ x,
                           int n) {
  int idx = blockIdx.x * THREADS + threadIdx.x;
  if (idx < n) x[idx] += p[idx];
}

// ---------------------------------------------------------------------------
// scalar relpos (kept for S=14 windows only)
__global__ void relpos_kernel(const u16* __restrict__ qkvb,
                              const float* __restrict__ rh_tab,
                              const float* __restrict__ rw_tab,
                              u16* __restrict__ relh,
                              u16* __restrict__ relw,
                              int S, int total) {
  int idx = blockIdx.x * THREADS + threadIdx.x;
  if (idx >= total) return;
  int k = idx % S;
  int r = idx / S;
  int qw = r % S; r /= S;
  int qh = r % S; r /= S;
  int head = r % 12;
  int win = r / 12;
  int seq = S * S;
  int tok = win * seq + qh * S + qw;
  const u16* q = qkvb + (size_t)tok * 2304 + head * 64;
  const float* rh = rh_tab + (size_t)(qh - k + S - 1) * 64;
  const float* rw = rw_tab + (size_t)(qw - k + S - 1) * 64;
  float sh = 0.f, sw = 0.f;
#pragma unroll
  for (int d0 = 0; d0 < 64; d0 += 8) {
    uint4 qv = *reinterpret_cast<const uint4*>(q + d0);
    u16 qs[8];
    *reinterpret_cast<uint4*>(qs) = qv;
#pragma unroll
    for (int i = 0; i < 8; ++i) {
      float qq = bf2f(qs[i]);
      sh = fmaf(qq, rh[d0 + i], sh);
      sw = fmaf(qq, rw[d0 + i], sw);
    }
  }
  relh[idx] = f2bf(sh * 8.0f);
  relw[idx] = f2bf(sw * 8.0f);
}

// ---------------------------------------------------------------------------
// MFMA flash attention, swapped-QK^T form.
// S=64: DOUBLE-BUFFERED K/V staging — prefetch tile t+1 (gload16 K, V->regs)
// before computing tile t; vmcnt+V-write after compute; ONE barrier/tile.
// LDS carve S=64: Kl[2] 8K | Vt[2] 8K | Pl 4K | RHl 4K u16 = 49152 B.
// S=14 keeps single-buffer path: Kl 4K | Vt 4K | Pl 4K | RH 1280*4 | RW
// 1280*4 = 29696 B.
// Vt swizzle: row d holds key at pos key ^ ((d&7)<<3).
// ---------------------------------------------------------------------------
template <int S>
__global__ __launch_bounds__(256)
void attn_mfma_kernel(const u16* __restrict__ qkvb,
                      const u16* __restrict__ RHt,
                      const u16* __restrict__ RWt,
                      u16* __restrict__ out) {
  constexpr int SEQ = S * S;
  constexpr int NKT = (SEQ + 63) / 64;
  constexpr bool DB = (S == 64);
  constexpr int BIAS_N = (S == 14) ? 320 : 1024;
  extern __shared__ __attribute__((aligned(16))) u16 smem[];
  u16* KlA[2];
  u16* VtA[2];
  u16* Plb;
  u16* RHlb;
  u16* RWlb = nullptr;
  if constexpr (DB) {
    KlA[0] = smem;          KlA[1] = smem + 4096;
    VtA[0] = smem + 8192;   VtA[1] = smem + 12288;
    Plb = smem + 16384;
    RHlb = smem + 20480;
  } else {
    KlA[0] = smem;          KlA[1] = smem;
    VtA[0] = smem + 4096;   VtA[1] = smem + 4096;
    Plb = smem + 8192;
    RHlb = smem + 12288;
    RWlb = RHlb + 4 * BIAS_N;
  }

  const int t = threadIdx.x;
  const int w = t >> 6;
  const int l = t & 63;
  const int g = l >> 4;
  const int q = l & 15;
  const int bn = blockIdx.y;
  const int win = bn / 12, head = bn % 12;
  const int qbase = blockIdx.x * 64 + w * 16;
  const size_t tokbase = (size_t)win * SEQ;
  u16* Pl = Plb + w * 1024;
  u16* RHl = RHlb + w * BIAS_N;
  u16* RWl = RWlb + w * BIAS_N;

  {  // stage bias rows per wave, TRANSPOSED: [k_idx*16 + q_local]
    int ql = l >> 2;
    int qglob = qbase + ql;
    if (qglob > SEQ - 1) qglob = SEQ - 1;
    int qh = qglob / S, qw = qglob - qh * S;
    size_t bh = (((size_t)bn * S + qh) * S + qw) * S;
    for (int i = l & 3; i < S; i += 4) {
      RHl[i * 16 + ql] = RHt[bh + i];
      if constexpr (S == 14) RWl[i * 16 + ql] = RWt[bh + i];
    }
  }

  // S=64: rw bias is lane-resident (kw = sub*16 + g*4 + reg is lane-fixed)
  float rwreg[4][4];
  if constexpr (S == 64) {
    int qglob = qbase + q;
    size_t rwb = (((size_t)bn * 64 + (qglob >> 6)) * 64 + (qglob & 63)) * 64;
#pragma unroll
    for (int sub = 0; sub < 4; ++sub)
#pragma unroll
      for (int reg = 0; reg < 4; ++reg)
        rwreg[sub][reg] = bf2f(RWt[rwb + sub * 16 + g * 4 + reg]);
  }

  bf16x8 qf[2];
  {
    int qglob = qbase + q;
    if (qglob > SEQ - 1) qglob = SEQ - 1;
    const u16* qp = qkvb + (tokbase + qglob) * 2304 + head * 64 + g * 8;
    qf[0] = *reinterpret_cast<const bf16x8*>(qp);
    qf[1] = *reinterpret_cast<const bf16x8*>(qp + 32);
  }

  float m_run = -1e30f, l_run = 0.f;
  f32x4 Oacc[4];
#pragma unroll
  for (int dn = 0; dn < 4; ++dn) Oacc[dn] = (f32x4){0.f, 0.f, 0.f, 0.f};

  const int rr = l >> 3;
  const int kcc = ((l & 7) ^ rr) * 8;  // inverse-swizzled source chunk
  const int vkey = t & 63, vdg = t >> 6;

  auto stageK = [&](int kt, u16* Kd) {
#pragma unroll
    for (int j = 0; j < 2; ++j) {
      int kk = kt * 64 + w * 16 + j * 8 + rr;
      if (kk > SEQ - 1) kk = SEQ - 1;
      gload16(qkvb + (tokbase + kk) * 2304 + 768 + head * 64 + kcc,
              &Kd[w * 1024 + j * 512]);
    }
  };
  auto loadV = [&](int kt, uint4& a, uint4& b) {
    int kk = kt * 64 + vkey;
    if (kk > SEQ - 1) kk = SEQ - 1;
    const uint4* src = reinterpret_cast<const uint4*>(
        qkvb + (tokbase + kk) * 2304 + 1536 + head * 64 + vdg * 16);
    a = src[0];
    b = src[1];
  };
  auto writeV = [&](uint4 a, uint4 b, u16* Vd) {
    u16 arr[16];
    *reinterpret_cast<uint4*>(&arr[0]) = a;
    *reinterpret_cast<uint4*>(&arr[8]) = b;
#pragma unroll
    for (int i = 0; i < 16; ++i)
      Vd[(vdg * 16 + i) * 64 + (vkey ^ ((i & 7) << 3))] = arr[i];
  };

  auto computeTile = [&](int kt, u16* Kl, u16* Vt) {
    const int k0 = kt * 64;
    // ---- S^T = K·Q^T : lane holds 16 scores of query q = l&15
    f32x4 Sacc[4];
#pragma unroll
    for (int sub = 0; sub < 4; ++sub) {
      Sacc[sub] = (f32x4){0.f, 0.f, 0.f, 0.f};
#pragma unroll
      for (int kc = 0; kc < 2; ++kc) {
        int key = sub * 16 + q;
        int chunk = (kc * 4 + g) ^ (key & 7);
        bf16x8 kfr = *reinterpret_cast<const bf16x8*>(&Kl[key * 64 + (chunk << 3)]);
        Sacc[sub] = MFMA16(kfr, qf[kc], Sacc[sub]);  // swapped operands
      }
    }

    // ---- bias + lane-local softmax
    float sv[4][4];
    float tmax = -1e30f;
    if constexpr (S == 64) {
      float rhv = bf2f(RHl[kt * 16 + q]);
#pragma unroll
      for (int sub = 0; sub < 4; ++sub)
#pragma unroll
        for (int reg = 0; reg < 4; ++reg) {
          float s = Sacc[sub][reg] + rhv + rwreg[sub][reg];
          sv[sub][reg] = s;
          tmax = fmaxf(tmax, s);
        }
    } else {
#pragma unroll
      for (int sub = 0; sub < 4; ++sub)
#pragma unroll
        for (int reg = 0; reg < 4; ++reg) {
          int key = k0 + sub * 16 + g * 4 + reg;
          float s = -1e30f;
          if (key < SEQ) {
            int kh = key / S, kw = key - kh * S;
            s = Sacc[sub][reg] + bf2f(RHl[kh * 16 + q]) + bf2f(RWl[kw * 16 + q]);
          }
          sv[sub][reg] = s;
          tmax = fmaxf(tmax, s);
        }
    }
    tmax = fmaxf(tmax, __shfl_xor(tmax, 16));
    tmax = fmaxf(tmax, __shfl_xor(tmax, 32));

    if (!__all(tmax - m_run <= 8.0f)) {  // defer-max: rescale only on growth
      float mn = fmaxf(m_run, tmax);
      float sc = __expf(m_run - mn);
      l_run *= sc;
      m_run = mn;
#pragma unroll
      for (int reg = 0; reg < 4; ++reg) {
        float scq = __shfl(sc, g * 4 + reg);  // O-row q' = g*4+reg state
#pragma unroll
        for (int dn = 0; dn < 4; ++dn) Oacc[dn][reg] *= scq;
      }
    }

    float psum = 0.f;
#pragma unroll
    for (int sub = 0; sub < 4; ++sub)
#pragma unroll
      for (int pr = 0; pr < 2; ++pr) {
        float p0 = __expf(sv[sub][2 * pr] - m_run);
        float p1 = __expf(sv[sub][2 * pr + 1] - m_run);
        psum += p0 + p1;
        u32 pk = f2bf2(p0, p1);  // v_cvt_pk_bf16_f32
        int idx = (q * 64 + sub * 16 + g * 4 + pr * 2) ^ ((q & 7) << 3);
        *reinterpret_cast<u32*>(&Pl[idx]) = pk;
      }
    psum += __shfl_xor(psum, 16);
    psum += __shfl_xor(psum, 32);
    l_run += psum;

    // ---- PV: O += P @ V (A = P from swizzled LDS, B = V^T swizzled rows)
#pragma unroll
    for (int kc = 0; kc < 2; ++kc) {
      int chunk = (kc * 4 + g) ^ (q & 7);
      bf16x8 pa = *reinterpret_cast<const bf16x8*>(&Pl[q * 64 + (chunk << 3)]);
#pragma unroll
      for (int dn = 0; dn < 4; ++dn) {
        bf16x8 vb = *reinterpret_cast<const bf16x8*>(
            &Vt[(dn * 16 + q) * 64 + (chunk << 3)]);
        Oacc[dn] = MFMA16(pa, vb, Oacc[dn]);
      }
    }
  };

  if constexpr (DB) {
    uint4 va, vb0;
    stageK(0, KlA[0]);
    loadV(0, va, vb0);
    asm volatile("s_waitcnt vmcnt(0)" ::: "memory");
    writeV(va, vb0, VtA[0]);
    __syncthreads();
    for (int kt = 0; kt < NKT; ++kt) {
      const int cur = kt & 1;
      const bool pf = (kt + 1 < NKT);
      if (pf) {            // prefetch next tile into idle buffer
        stageK(kt + 1, KlA[cur ^ 1]);
        loadV(kt + 1, va, vb0);
      }
      computeTile(kt, KlA[cur], VtA[cur]);
      if (pf) {
        asm volatile("s_waitcnt vmcnt(0)" ::: "memory");
        writeV(va, vb0, VtA[cur ^ 1]);
      }
      __syncthreads();
    }
  } else {
    for (int kt = 0; kt < NKT; ++kt) {
      __syncthreads();
      stageK(kt, KlA[0]);
      uint4 va, vb0;
      loadV(kt, va, vb0);
      writeV(va, vb0, VtA[0]);
      asm volatile("s_waitcnt vmcnt(0)" ::: "memory");
      __syncthreads();
      computeTile(kt, KlA[0], VtA[0]);
    }
  }

  // ---- epilogue: O rows are queries g*4+reg; softmax state lives lane q
  float invq = 1.0f / l_run;
#pragma unroll
  for (int reg = 0; reg < 4; ++reg) {
    int ql = g * 4 + reg;
    int qglob = qbase + ql;
    if (qglob >= SEQ) continue;
    float inv = __shfl(invq, ql);
    u16* op = out + (tokbase + qglob) * 768 + head * 64;
#pragma unroll
    for (int dn = 0; dn < 4; ++dn)
      op[dn * 16 + q] = f2bf(Oacc[dn][reg] * inv);
  }
}

// ---------------------------------------------------------------------------
__global__ void neck_im2col_kernel(const u16* __restrict__ ln,
                                   u16* __restrict__ out) {
  int idx = blockIdx.x * THREADS + threadIdx.x;
  if (idx >= 4096 * 2304) return;
  int col = idx % 2304, tok = idx / 2304;
  int n9 = col >> 8, c = col & 255;
  int y = tok >> 6, x = tok & 63;
  int yy = y + n9 / 3 - 1, xx = x + n9 % 3 - 1;
  out[idx] = (yy >= 0 && yy < 64 && xx >= 0 && xx < 64)
                 ? ln[((size_t)yy * 64 + xx) * 256 + c]
                 : (u16)0;
}

__global__ void ln2d_out_kernel(const float* __restrict__ in,
                                const float* __restrict__ w,
                                const float* __restrict__ b,
                                float* __restrict__ out) {
  __shared__ float red[4];
  int tok = blockIdx.x, t = threadIdx.x;
  float v = in[(size_t)tok * 256 + t];
  float s = block_reduce_sum256(v, red);
  float m = s / 256.f;
  float dv = v - m;
  float s2 = block_reduce_sum256(dv * dv, red);
  float inv = rsqrtf(s2 / 256.f + 1e-6f);
  out[(size_t)t * 4096 + tok] = dv * inv * w[t] + b[t];
}

// ---------------------------------------------------------------------------
extern "C" void kernel_launch(void* const* d_in, const int* in_sizes, int n_in,
                              void* d_out, int out_size, void* d_ws,
                              size_t ws_size, hipStream_t stream) {
  const float* pixel_values = (const float*)d_in[0];
  const float* patch_w = (const float*)d_in[1];
  const float* patch_b = (const float*)d_in[2];
  const float* pos_embed = (const float*)d_in[3];
  const float* ln1_w = (const float*)d_in[4];
  const float* ln1_b = (const float*)d_in[5];
  const float* qkv_w = (const float*)d_in[6];
  const float* qkv_b = (const float*)d_in[7];
  const float* proj_w = (const float*)d_in[8];
  const float* proj_b = (const float*)d_in[9];
  const float* rel_h0 = (const float*)d_in[10];
  const float* rel_w0 = (const float*)d_in[11];
  const float* rel_h1 = (const float*)d_in[12];
  const float* rel_w1 = (const float*)d_in[13];
  const float* ln2_w = (const float*)d_in[14];
  const float* ln2_b = (const float*)d_in[15];
  const float* mlp1_w = (const float*)d_in[16];
  const float* mlp1_b = (const float*)d_in[17];
  const float* mlp2_w = (const float*)d_in[18];
  const float* mlp2_b = (const float*)d_in[19];
  const float* neck1_w = (const float*)d_in[20];
  const float* nln1_w = (const float*)d_in[21];
  const float* nln1_b = (const float*)d_in[22];
  const float* neck2_w = (const float*)d_in[23];
  const float* nln2_w = (const float*)d_in[24];
  const float* nln2_b = (const float*)d_in[25];
  float* out = (float*)d_out;

  // ---- workspace layout (~114 MB) ----
  float* X = (float*)d_ws;                       // 3,145,728 f32
  u16* Xb = (u16*)(X + 3145728);                 // 3,145,728 u16
  float* H = (float*)(Xb + 3145728);             // 3,763,200 f32
  u16* Ab1 = (u16*)(H + 3763200);                // 3,763,200 u16
  u16* Ab2 = Ab1 + 3763200;                      // 12,582,912 u16
  u16* QKVb = Ab2 + 12582912;                    // 11,289,600 u16
  u16* RHb = QKVb + 11289600;                    // 3,145,728 u16
  u16* RWb = RHb + 3145728;                      // 3,145,728 u16
  u16* AOb = RWb + 3145728;                      // 3,763,200 u16
  u16* Wb = AOb + 3763200;                       // 2,359,296 u16 (weight scratch)
  u16* RTb = Wb + 2359296;                       // 8,128 u16 (rel_h1 bf16)
  u16* RTb2 = RTb + 8128;                        // 8,128 u16 (rel_w1 bf16)
  u16* LNb = Ab2 + 11520000;                     // 1,048,576 u16 (inside Ab2 tail)

#define CVT(src, n) f2b_kernel<<<((n) / 4 + THREADS - 1) / THREADS, THREADS, 0, stream>>>(src, Wb, n)

  // ---- patch embed ----
  im2col_patch_kernel<<<12288, THREADS, 0, stream>>>(pixel_values, Ab2);
  CVT(patch_w, 589824);
  gemm_bf16<0, 64><<<dim3(12, 32), THREADS, 0, stream>>>(
      Ab2, Wb, patch_b, pos_embed, X, nullptr, 4096, 768, 768);

  // ================= layer 0 (windowed, S=14, 25 windows) ==================
  ln_row_kernel<<<4096, THREADS, 0, stream>>>(X, ln1_w, ln1_b, Ab2, 768);
  win_part_kernel<<<14700, THREADS, 0, stream>>>(Ab2, Ab1);
  CVT(qkv_w, 1769472);
  gemm_bf16<2, 128><<<dim3(18, 39), THREADS, 0, stream>>>(
      Ab1, Wb, qkv_b, nullptr, QKVb, nullptr, 4900, 2304, 768);
  {
    int total = 25 * 12 * 14 * 14 * 14;
    relpos_kernel<<<(total + THREADS - 1) / THREADS, THREADS, 0, stream>>>(
        QKVb, rel_h0, rel_w0, RHb, RWb, 14, total);
  }
  attn_mfma_kernel<14><<<dim3(4, 300), THREADS, 29696, stream>>>(QKVb, RHb, RWb, AOb);
  CVT(proj_w, 589824);
  gemm_bf16<0, 64><<<dim3(12, 39), THREADS, 0, stream>>>(
      AOb, Wb, proj_b, nullptr, H, nullptr, 4900, 768, 768);
  win_unpart_add_kernel<<<12288, THREADS, 0, stream>>>(H, X);
  // MLP 0
  ln_row_kernel<<<4096, THREADS, 0, stream>>>(X, ln2_w, ln2_b, Ab1, 768);
  CVT(mlp1_w, 2359296);
  gemm_bf16<1, 128><<<dim3(24, 32), THREADS, 0, stream>>>(
      Ab1, Wb, mlp1_b, nullptr, Ab2, nullptr, 4096, 3072, 768);
  CVT(mlp2_w, 2359296);
  gemm_bf16<0, 64><<<dim3(12, 32), THREADS, 0, stream>>>(
      Ab2, Wb, mlp2_b, X, X, nullptr, 4096, 768, 3072);

  // ================= layer 1 (global, S=64) ================================
  ln_row_kernel<<<4096, THREADS, 0, stream>>>(X, ln1_w + 768, ln1_b + 768, Ab1, 768);
  CVT(qkv_w + (size_t)2304 * 768, 1769472);
  gemm_bf16<2, 128><<<dim3(18, 32), THREADS, 0, stream>>>(
      Ab1, Wb, qkv_b + 2304, nullptr, QKVb, nullptr, 4096, 2304, 768);
  // rel tables -> bf16, then relpos as batched MFMA GEMMs
  f2b_kernel<<<8, THREADS, 0, stream>>>(rel_h1, RTb, 8128);
  f2b_kernel<<<8, THREADS, 0, stream>>>(rel_w1, RTb2, 8128);
  relpos_mfma_kernel<0><<<768, THREADS, 0, stream>>>(QKVb, RTb, RHb);
  relpos_mfma_kernel<1><<<768, THREADS, 0, stream>>>(QKVb, RTb2, RWb);
  attn_mfma_kernel<64><<<dim3(64, 12), THREADS, 49152, stream>>>(QKVb, RHb, RWb, AOb);
  CVT(proj_w + (size_t)768 * 768, 589824);
  gemm_bf16<0, 64><<<dim3(12, 32), THREADS, 0, stream>>>(
      AOb, Wb, proj_b + 768, nullptr, H, nullptr, 4096, 768, 768);
  add_kernel<<<12288, THREADS, 0, stream>>>(H, X, 4096 * 768);
  // MLP 1
  ln_row_kernel<<<4096, THREADS, 0, stream>>>(X, ln2_w + 768, ln2_b + 768, Ab1, 768);
  CVT(mlp1_w + (size_t)3072 * 768, 2359296);
  gemm_bf16<1, 128><<<dim3(24, 32), THREADS, 0, stream>>>(
      Ab1, Wb, mlp1_b + 3072, nullptr, Ab2, nullptr, 4096, 3072, 768);
  CVT(mlp2_w + (size_t)768 * 3072, 2359296);
  gemm_bf16<3, 64><<<dim3(12, 32), THREADS, 0, stream>>>(
      Ab2, Wb, mlp2_b + 768, X, X, Xb, 4096, 768, 3072);

  // ================= neck ==================================================
  CVT(neck1_w, 196608);
  gemm_bf16<0, 64><<<dim3(4, 32), THREADS, 0, stream>>>(
      Xb, Wb, nullptr, nullptr, H, nullptr, 4096, 256, 768);
  ln_row_kernel<<<4096, THREADS, 0, stream>>>(H, nln1_w, nln1_b, LNb, 256);
  neck2w_kernel<<<2304, THREADS, 0, stream>>>(neck2_w, Wb);
  neck_im2col_kernel<<<36864, THREADS, 0, stream>>>(LNb, Ab2);
  gemm_bf16<0, 64><<<dim3(4, 32), THREADS, 0, stream>>>(
      Ab2, Wb, nullptr, nullptr, H, nullptr, 4096, 256, 2304);
  ln2d_out_kernel<<<4096, THREADS, 0, stream>>>(H, nln2_w, nln2_b, out);
}

// Round 11
// 1026.285 us; speedup vs baseline: 1.0033x; 1.0033x over previous
//
#include <hip/hip_runtime.h>
#include <hip/hip_bf16.h>
#include <cmath>
#include <cstddef>

#define THREADS 256
typedef unsigned short u16;
typedef unsigned int u32;
typedef __attribute__((ext_vector_type(8))) short bf16x8;
typedef __attribute__((ext_vector_type(4))) float f32x4;
#define MFMA16(a, b, c) __builtin_amdgcn_mfma_f32_16x16x32_bf16(a, b, c, 0, 0, 0)

__device__ __forceinline__ float bf2f(u16 u) {
  union { u32 i; float f; } x; x.i = ((u32)u) << 16; return x.f;
}
// native bf16 conversion (compiler emits v_cvt_pk_bf16_f32 for pairs)
__device__ __forceinline__ u16 f2bf(float f) {
  __hip_bfloat16 h = __float2bfloat16(f);
  return *reinterpret_cast<u16*>(&h);
}
__device__ __forceinline__ u32 f2bf2(float a, float b) {
  __hip_bfloat162 h = __float22bfloat162_rn(make_float2(a, b));
  return *reinterpret_cast<u32*>(&h);
}
// convert 8 f32 (two float4) -> packed uint4 of 8 bf16
__device__ __forceinline__ uint4 cvt8(float4 x0, float4 x1) {
  return make_uint4(f2bf2(x0.x, x0.y), f2bf2(x0.z, x0.w),
                    f2bf2(x1.x, x1.y), f2bf2(x1.z, x1.w));
}

// async global->LDS, 16B per lane; LDS dest is wave-uniform base + lane*16
__device__ __forceinline__ void gload16(const u16* g, u16* l) {
  __builtin_amdgcn_global_load_lds(
      (const __attribute__((address_space(1))) unsigned int*)g,
      (__attribute__((address_space(3))) unsigned int*)l, 16, 0, 0);
}

__device__ __forceinline__ float block_reduce_sum256(float v, float* red4) {
  for (int off = 32; off > 0; off >>= 1) v += __shfl_down(v, off);
  __syncthreads();
  if ((threadIdx.x & 63) == 0) red4[threadIdx.x >> 6] = v;
  __syncthreads();
  return red4[0] + red4[1] + red4[2] + red4[3];
}

// ---------------------------------------------------------------------------
// neck conv2 weight: src OIHW [256][256][3][3] -> dst [o][(ky*3+kx)*256 + c]
__global__ void neck2w_kernel(const float* __restrict__ src,
                              u16* __restrict__ dst) {
  int idx = blockIdx.x * THREADS + threadIdx.x;
  if (idx >= 256 * 2304) return;
  int o = idx / 2304, r = idx % 2304;
  int n9 = r >> 8, c = r & 255;
  dst[idx] = f2bf(src[(size_t)(o * 256 + c) * 9 + n9]);
}

// ---------------------------------------------------------------------------
__global__ void im2col_patch_kernel(const float* __restrict__ img,
                                    u16* __restrict__ out) {
  int idx = blockIdx.x * THREADS + threadIdx.x;
  if (idx >= 4096 * 768) return;
  int col = idx % 768, tok = idx / 768;
  int ph = tok / 64, pw = tok % 64;
  int c = col / 256, r = col % 256;
  int i = r / 16, j = r % 16;
  out[idx] = f2bf(img[(size_t)(c * 1024 + ph * 16 + i) * 1024 + pw * 16 + j]);
}

// ---------------------------------------------------------------------------
// MFMA GEMM: C[M,N] = A[M,K]bf16 @ B[N,K]^T, fp32 accum. BF32: B is f32 and
// gets converted during staging (reg-stage + cvt_pk + ds_write_b128 into the
// same swizzled slots gload16 would fill); else B is bf16 via gload16.
// 128xBN tile (BN=128 or 64), BK=64, 4 waves.
// MODE 0: f32 out (+bias)(+res); 1: GELU->bf16; 2: bf16, q-cols x0.125;
// MODE 3: f32 out + bf16 mirror out2.
// ---------------------------------------------------------------------------
template <int MODE, int BN, int BF32>
__global__ __launch_bounds__(256)
void gemm_bf16(const u16* __restrict__ A, const void* __restrict__ Bv,
               const float* __restrict__ bias, const float* __restrict__ res,
               void* __restrict__ out, void* __restrict__ out2,
               int M, int N, int K) {
  constexpr int NF = BN / 32;  // per-wave n fragments
  __shared__ __attribute__((aligned(16))) u16 As[128 * 64];
  __shared__ __attribute__((aligned(16))) u16 Bs[BN * 64];
  const int t = threadIdx.x;
  const int w = t >> 6, l = t & 63;
  const int m0 = blockIdx.y * 128, n0 = blockIdx.x * BN;
  const int wm = (w >> 1) * 64, wn = (w & 1) * (BN / 2);
  f32x4 acc[4][NF];
#pragma unroll
  for (int i = 0; i < 4; ++i)
#pragma unroll
    for (int j = 0; j < NF; ++j) acc[i][j] = (f32x4){0.f, 0.f, 0.f, 0.f};

  // staging source addresses (inverse-swizzled chunk per lane)
  const int rr = l >> 3;                 // row-in-8 group
  const int cc = ((l & 7) ^ rr) * 8;     // source chunk offset (elements)
  const u16* aP[4];
  const u16* bP[NF];
  const float* bPf[NF];
#pragma unroll
  for (int j = 0; j < 4; ++j) {
    int ar = m0 + w * 32 + j * 8 + rr;
    if (ar >= M) ar = M - 1;
    aP[j] = A + (size_t)ar * K + cc;
  }
#pragma unroll
  for (int j = 0; j < NF; ++j) {
    size_t brow = (size_t)(n0 + w * (BN / 4) + j * 8 + rr);
    if (BF32) bPf[j] = (const float*)Bv + brow * K + cc;
    else      bP[j]  = (const u16*)Bv + brow * K + cc;
  }
  u16* asw = &As[w * 2048];
  u16* bsw = &Bs[w * (BN * 16)];

  for (int k0 = 0; k0 < K; k0 += 64) {
    __syncthreads();
#pragma unroll
    for (int j = 0; j < 4; ++j) gload16(aP[j] + k0, asw + j * 512);
    if constexpr (BF32) {
#pragma unroll
      for (int j = 0; j < NF; ++j) {
        float4 x0 = *reinterpret_cast<const float4*>(bPf[j] + k0);
        float4 x1 = *reinterpret_cast<const float4*>(bPf[j] + k0 + 4);
        *reinterpret_cast<uint4*>(bsw + j * 512 + l * 8) = cvt8(x0, x1);
      }
    } else {
#pragma unroll
      for (int j = 0; j < NF; ++j) gload16(bP[j] + k0, bsw + j * 512);
    }
    asm volatile("s_waitcnt vmcnt(0)" ::: "memory");
    __syncthreads();
#pragma unroll
    for (int kc = 0; kc < 2; ++kc) {
      bf16x8 af[4], bf[NF];
#pragma unroll
      for (int i = 0; i < 4; ++i) {
        int ar = wm + i * 16 + (l & 15);
        int ac = (kc * 4 + (l >> 4)) ^ (ar & 7);
        af[i] = *reinterpret_cast<const bf16x8*>(&As[ar * 64 + ac * 8]);
      }
#pragma unroll
      for (int j = 0; j < NF; ++j) {
        int br = wn + j * 16 + (l & 15);
        int bc = (kc * 4 + (l >> 4)) ^ (br & 7);
        bf[j] = *reinterpret_cast<const bf16x8*>(&Bs[br * 64 + bc * 8]);
      }
#pragma unroll
      for (int i = 0; i < 4; ++i)
#pragma unroll
        for (int j = 0; j < NF; ++j)
          acc[i][j] = MFMA16(af[i], bf[j], acc[i][j]);
    }
  }

#pragma unroll
  for (int i = 0; i < 4; ++i) {
#pragma unroll
    for (int reg = 0; reg < 4; ++reg) {
      int m = m0 + wm + i * 16 + (l >> 4) * 4 + reg;
      if (m >= M) continue;
#pragma unroll
      for (int j = 0; j < NF; ++j) {
        int n = n0 + wn + j * 16 + (l & 15);
        float v = acc[i][j][reg];
        if (bias) v += bias[n];
        if (MODE == 0 || MODE == 3) {
          if (res) v += res[(size_t)m * N + n];
          ((float*)out)[(size_t)m * N + n] = v;
          if (MODE == 3) ((u16*)out2)[(size_t)m * N + n] = f2bf(v);
        } else if (MODE == 1) {
          v = 0.5f * v * (1.0f + erff(v * 0.70710678118654752f));
          ((u16*)out)[(size_t)m * N + n] = f2bf(v);
        } else {  // MODE 2
          float sc = (n < 768) ? 0.125f : 1.0f;
          ((u16*)out)[(size_t)m * N + n] = f2bf(v * sc);
        }
      }
    }
  }
}

// ---------------------------------------------------------------------------
// relpos as batched 64x64x64 MFMA GEMM (S=64 only). Rtab is f32 [127][64],
// converted to bf16 during LDS staging (reg-stage + cvt_pk).
// WHICH=0 (rel_h): fixed qh -> C[qw][k] = Q[qh,qw,:]·Rh[qh-k+63,:]^T
// WHICH=1 (rel_w): fixed qw -> C[qh][k] = Q[qh,qw,:]·Rw[qw-k+63,:]^T
// ---------------------------------------------------------------------------
template <int WHICH>
__global__ __launch_bounds__(256)
void relpos_mfma_kernel(const u16* __restrict__ qkvb,
                        const float* __restrict__ Rtab,
                        u16* __restrict__ relout) {
  __shared__ __attribute__((aligned(16))) u16 Ql[64 * 64];
  __shared__ __attribute__((aligned(16))) u16 Rl[64 * 64];
  const int t = threadIdx.x, w = t >> 6, l = t & 63;
  const int head = blockIdx.x >> 6;
  const int fixed = blockIdx.x & 63;  // qh (WHICH=0) or qw (WHICH=1)
  const int rr = l >> 3;
  const int cc = ((l & 7) ^ rr) * 8;  // inverse-swizzled source chunk

#pragma unroll
  for (int j = 0; j < 2; ++j) {
    int row = w * 16 + j * 8 + rr;
    int tok = (WHICH == 0) ? (fixed * 64 + row) : (row * 64 + fixed);
    gload16(qkvb + (size_t)tok * 2304 + head * 64 + cc, &Ql[w * 1024 + j * 512]);
    int rrow = fixed - row + 63;  // always in [0,126]
    const float* rs = Rtab + (size_t)rrow * 64 + cc;
    float4 x0 = *reinterpret_cast<const float4*>(rs);
    float4 x1 = *reinterpret_cast<const float4*>(rs + 4);
    *reinterpret_cast<uint4*>(&Rl[w * 1024 + j * 512 + l * 8]) = cvt8(x0, x1);
  }
  asm volatile("s_waitcnt vmcnt(0)" ::: "memory");
  __syncthreads();

  f32x4 acc[4];
#pragma unroll
  for (int j = 0; j < 4; ++j) acc[j] = (f32x4){0.f, 0.f, 0.f, 0.f};
#pragma unroll
  for (int kc = 0; kc < 2; ++kc) {
    int ar = w * 16 + (l & 15);
    int ac = (kc * 4 + (l >> 4)) ^ (ar & 7);
    bf16x8 af = *reinterpret_cast<const bf16x8*>(&Ql[ar * 64 + ac * 8]);
#pragma unroll
    for (int j = 0; j < 4; ++j) {
      int br = j * 16 + (l & 15);
      int bc = (kc * 4 + (l >> 4)) ^ (br & 7);
      bf16x8 bf = *reinterpret_cast<const bf16x8*>(&Rl[br * 64 + bc * 8]);
      acc[j] = MFMA16(af, bf, acc[j]);
    }
  }

#pragma unroll
  for (int j = 0; j < 4; ++j) {
#pragma unroll
    for (int reg = 0; reg < 4; ++reg) {
      int m = w * 16 + (l >> 4) * 4 + reg;  // qw (WHICH=0) / qh (WHICH=1)
      int n = j * 16 + (l & 15);            // k
      size_t o = (WHICH == 0)
                     ? ((((size_t)head * 64 + fixed) * 64 + m) * 64 + n)
                     : ((((size_t)head * 64 + m) * 64 + fixed) * 64 + n);
      relout[o] = f2bf(acc[j][reg] * 8.0f);
    }
  }
}

// ---------------------------------------------------------------------------
__global__ void ln_row_kernel(const float* __restrict__ in,
                              const float* __restrict__ w,
                              const float* __restrict__ b,
                              u16* __restrict__ out, int D) {
  __shared__ float red[4];
  size_t base = (size_t)blockIdx.x * D;
  float s = 0.f, s2 = 0.f;
  for (int i = threadIdx.x; i < D; i += THREADS) {
    float v = in[base + i];
    s += v; s2 += v * v;
  }
  s = block_reduce_sum256(s, red);
  s2 = block_reduce_sum256(s2, red);
  float m = s / (float)D;
  float var = s2 / (float)D - m * m;
  float inv = rsqrtf(var + 1e-6f);
  for (int i = threadIdx.x; i < D; i += THREADS) {
    float v = in[base + i];
    out[base + i] = f2bf((v - m) * inv * w[i] + b[i]);
  }
}

// ---------------------------------------------------------------------------
__global__ void win_part_kernel(const u16* __restrict__ h,
                                u16* __restrict__ out) {
  int idx = blockIdx.x * THREADS + threadIdx.x;
  if (idx >= 4900 * 768) return;
  int c = idx % 768;
  int tok = idx / 768;
  int win = tok / 196, r = tok % 196;
  int wy = r / 14, wx = r % 14;
  int gy = (win / 5) * 14 + wy;
  int gx = (win % 5) * 14 + wx;
  out[idx] = (gy < 64 && gx < 64) ? h[((size_t)gy * 64 + gx) * 768 + c] : (u16)0;
}

__global__ void win_unpart_add_kernel(const float* __restrict__ p,
                                      float* __restrict__ x) {
  int idx = blockIdx.x * THREADS + threadIdx.x;
  if (idx >= 4096 * 768) return;
  int c = idx % 768;
  int tok = idx / 768;
  int gy = tok / 64, gx = tok % 64;
  int win = (gy / 14) * 5 + (gx / 14);
  int wy = gy % 14, wx = gx % 14;
  x[idx] += p[((size_t)(win * 196 + wy * 14 + wx)) * 768 + c];
}

__global__ void add_kernel(const float* __restrict__ p, float* __restrict__ x,
                           int n) {
  int idx = blockIdx.x * THREADS + threadIdx.x;
  if (idx < n) x[idx] += p[idx];
}

// ---------------------------------------------------------------------------
// scalar relpos (kept for S=14 windows only)
__global__ void relpos_kernel(const u16* __restrict__ qkvb,
                              const float* __restrict__ rh_tab,
                              const float* __restrict__ rw_tab,
                              u16* __restrict__ relh,
                              u16* __restrict__ relw,
                              int S, int total) {
  int idx = blockIdx.x * THREADS + threadIdx.x;
  if (idx >= total) return;
  int k = idx % S;
  int r = idx / S;
  int qw = r % S; r /= S;
  int qh = r % S; r /= S;
  int head = r % 12;
  int win = r / 12;
  int seq = S * S;
  int tok = win * seq + qh * S + qw;
  const u16* q = qkvb + (size_t)tok * 2304 + head * 64;
  const float* rh = rh_tab + (size_t)(qh - k + S - 1) * 64;
  const float* rw = rw_tab + (size_t)(qw - k + S - 1) * 64;
  float sh = 0.f, sw = 0.f;
#pragma unroll
  for (int d0 = 0; d0 < 64; d0 += 8) {
    uint4 qv = *reinterpret_cast<const uint4*>(q + d0);
    u16 qs[8];
    *reinterpret_cast<uint4*>(qs) = qv;
#pragma unroll
    for (int i = 0; i < 8; ++i) {
      float qq = bf2f(qs[i]);
      sh = fmaf(qq, rh[d0 + i], sh);
      sw = fmaf(qq, rw[d0 + i], sw);
    }
  }
  relh[idx] = f2bf(sh * 8.0f);
  relw[idx] = f2bf(sw * 8.0f);
}

// ---------------------------------------------------------------------------
// MFMA flash attention, swapped-QK^T form (single-buffer, round-9 verified).
// Dynamic LDS carve:
//   Kl 4096 u16 | Vt 4096 u16 (XOR-swizzled, no pad) | Pl 4096 u16 |
//   RHl (S==14 ? 1280 : 4096) | RWl (S==14 ? 1280 : 0)
// S=64 total = 32768 B; S=14 = 29696 B.
// Vt swizzle: row d holds key at pos key ^ ((d&7)<<3).
// ---------------------------------------------------------------------------
template <int S>
__global__ __launch_bounds__(256)
void attn_mfma_kernel(const u16* __restrict__ qkvb,
                      const u16* __restrict__ RHt,
                      const u16* __restrict__ RWt,
                      u16* __restrict__ out) {
  constexpr int SEQ = S * S;
  constexpr int NKT = (SEQ + 63) / 64;
  constexpr int BIAS_N = (S == 14) ? 320 : 1024;
  extern __shared__ __attribute__((aligned(16))) u16 smem[];
  u16* Kl = smem;                       // 4096
  u16* Vt = smem + 4096;                // 4096
  u16* Plb = smem + 8192;               // 4096
  u16* RHlb = smem + 12288;             // 4*BIAS_N
  u16* RWlb = RHlb + 4 * BIAS_N;        // S==14 only

  const int t = threadIdx.x;
  const int w = t >> 6;
  const int l = t & 63;
  const int g = l >> 4;
  const int q = l & 15;
  const int bn = blockIdx.y;
  const int win = bn / 12, head = bn % 12;
  const int qbase = blockIdx.x * 64 + w * 16;
  const size_t tokbase = (size_t)win * SEQ;
  u16* Pl = Plb + w * 1024;
  u16* RHl = RHlb + w * BIAS_N;
  u16* RWl = RWlb + w * BIAS_N;

  {  // stage bias rows per wave, TRANSPOSED: [k_idx*16 + q_local]
    int ql = l >> 2;
    int qglob = qbase + ql;
    if (qglob > SEQ - 1) qglob = SEQ - 1;
    int qh = qglob / S, qw = qglob - qh * S;
    size_t bh = (((size_t)bn * S + qh) * S + qw) * S;
    for (int i = l & 3; i < S; i += 4) {
      RHl[i * 16 + ql] = RHt[bh + i];
      if constexpr (S == 14) RWl[i * 16 + ql] = RWt[bh + i];
    }
  }

  // S=64: rw bias is lane-resident (kw = sub*16 + g*4 + reg is lane-fixed)
  float rwreg[4][4];
  if constexpr (S == 64) {
    int qglob = qbase + q;
    size_t rwb = (((size_t)bn * 64 + (qglob >> 6)) * 64 + (qglob & 63)) * 64;
#pragma unroll
    for (int sub = 0; sub < 4; ++sub)
#pragma unroll
      for (int reg = 0; reg < 4; ++reg)
        rwreg[sub][reg] = bf2f(RWt[rwb + sub * 16 + g * 4 + reg]);
  }

  bf16x8 qf[2];
  {
    int qglob = qbase + q;
    if (qglob > SEQ - 1) qglob = SEQ - 1;
    const u16* qp = qkvb + (tokbase + qglob) * 2304 + head * 64 + g * 8;
    qf[0] = *reinterpret_cast<const bf16x8*>(qp);
    qf[1] = *reinterpret_cast<const bf16x8*>(qp + 32);
  }

  float m_run = -1e30f, l_run = 0.f;
  f32x4 Oacc[4];
#pragma unroll
  for (int dn = 0; dn < 4; ++dn) Oacc[dn] = (f32x4){0.f, 0.f, 0.f, 0.f};

  const int rr = l >> 3;
  const int kcc = ((l & 7) ^ rr) * 8;  // inverse-swizzled source chunk

  for (int kt = 0; kt < NKT; ++kt) {
    const int k0 = kt * 64;
    __syncthreads();
    {  // K tile via global_load_lds (linear LDS dest == swizzled slots)
#pragma unroll
      for (int j = 0; j < 2; ++j) {
        int kk = k0 + w * 16 + j * 8 + rr;
        if (kk > SEQ - 1) kk = SEQ - 1;
        gload16(qkvb + (tokbase + kk) * 2304 + 768 + head * 64 + kcc,
                &Kl[w * 1024 + j * 512]);
      }
    }
    {  // V transposed [d][key], XOR-swizzled: pos = key ^ ((d&7)<<3)
      int key = t & 63, dg = t >> 6;
      int kk = k0 + key; if (kk > SEQ - 1) kk = SEQ - 1;
      const uint4* src = reinterpret_cast<const uint4*>(
          qkvb + (tokbase + kk) * 2304 + 1536 + head * 64 + dg * 16);
      uint4 a = src[0], b = src[1];
      u16 arr[16];
      *reinterpret_cast<uint4*>(&arr[0]) = a;
      *reinterpret_cast<uint4*>(&arr[8]) = b;
#pragma unroll
      for (int i = 0; i < 16; ++i)
        Vt[(dg * 16 + i) * 64 + (key ^ ((i & 7) << 3))] = arr[i];
    }
    asm volatile("s_waitcnt vmcnt(0)" ::: "memory");
    __syncthreads();

    // ---- S^T = K·Q^T : lane holds 16 scores of query q = l&15
    f32x4 Sacc[4];
#pragma unroll
    for (int sub = 0; sub < 4; ++sub) {
      Sacc[sub] = (f32x4){0.f, 0.f, 0.f, 0.f};
#pragma unroll
      for (int kc = 0; kc < 2; ++kc) {
        int key = sub * 16 + q;
        int chunk = (kc * 4 + g) ^ (key & 7);
        bf16x8 kfr = *reinterpret_cast<const bf16x8*>(&Kl[key * 64 + (chunk << 3)]);
        Sacc[sub] = MFMA16(kfr, qf[kc], Sacc[sub]);  // swapped operands
      }
    }

    // ---- bias + lane-local softmax
    float sv[4][4];
    float tmax = -1e30f;
    if constexpr (S == 64) {
      float rhv = bf2f(RHl[kt * 16 + q]);
#pragma unroll
      for (int sub = 0; sub < 4; ++sub)
#pragma unroll
        for (int reg = 0; reg < 4; ++reg) {
          float s = Sacc[sub][reg] + rhv + rwreg[sub][reg];
          sv[sub][reg] = s;
          tmax = fmaxf(tmax, s);
        }
    } else {
#pragma unroll
      for (int sub = 0; sub < 4; ++sub)
#pragma unroll
        for (int reg = 0; reg < 4; ++reg) {
          int key = k0 + sub * 16 + g * 4 + reg;
          float s = -1e30f;
          if (key < SEQ) {
            int kh = key / S, kw = key - kh * S;
            s = Sacc[sub][reg] + bf2f(RHl[kh * 16 + q]) + bf2f(RWl[kw * 16 + q]);
          }
          sv[sub][reg] = s;
          tmax = fmaxf(tmax, s);
        }
    }
    tmax = fmaxf(tmax, __shfl_xor(tmax, 16));
    tmax = fmaxf(tmax, __shfl_xor(tmax, 32));

    if (!__all(tmax - m_run <= 8.0f)) {  // defer-max: rescale only on growth
      float mn = fmaxf(m_run, tmax);
      float sc = __expf(m_run - mn);
      l_run *= sc;
      m_run = mn;
#pragma unroll
      for (int reg = 0; reg < 4; ++reg) {
        float scq = __shfl(sc, g * 4 + reg);  // O-row q' = g*4+reg state
#pragma unroll
        for (int dn = 0; dn < 4; ++dn) Oacc[dn][reg] *= scq;
      }
    }

    float psum = 0.f;
#pragma unroll
    for (int sub = 0; sub < 4; ++sub)
#pragma unroll
      for (int pr = 0; pr < 2; ++pr) {
        float p0 = __expf(sv[sub][2 * pr] - m_run);
        float p1 = __expf(sv[sub][2 * pr + 1] - m_run);
        psum += p0 + p1;
        u32 pk = f2bf2(p0, p1);  // v_cvt_pk_bf16_f32
        int idx = (q * 64 + sub * 16 + g * 4 + pr * 2) ^ ((q & 7) << 3);
        *reinterpret_cast<u32*>(&Pl[idx]) = pk;
      }
    psum += __shfl_xor(psum, 16);
    psum += __shfl_xor(psum, 32);
    l_run += psum;

    // ---- PV: O += P @ V (A = P from swizzled LDS, B = V^T swizzled rows)
#pragma unroll
    for (int kc = 0; kc < 2; ++kc) {
      int chunk = (kc * 4 + g) ^ (q & 7);
      bf16x8 pa = *reinterpret_cast<const bf16x8*>(&Pl[q * 64 + (chunk << 3)]);
#pragma unroll
      for (int dn = 0; dn < 4; ++dn) {
        bf16x8 vb = *reinterpret_cast<const bf16x8*>(
            &Vt[(dn * 16 + q) * 64 + (chunk << 3)]);
        Oacc[dn] = MFMA16(pa, vb, Oacc[dn]);
      }
    }
  }

  // ---- epilogue: O rows are queries g*4+reg; softmax state lives lane q
  float invq = 1.0f / l_run;
#pragma unroll
  for (int reg = 0; reg < 4; ++reg) {
    int ql = g * 4 + reg;
    int qglob = qbase + ql;
    if (qglob >= SEQ) continue;
    float inv = __shfl(invq, ql);
    u16* op = out + (tokbase + qglob) * 768 + head * 64;
#pragma unroll
    for (int dn = 0; dn < 4; ++dn)
      op[dn * 16 + q] = f2bf(Oacc[dn][reg] * inv);
  }
}

// ---------------------------------------------------------------------------
__global__ void neck_im2col_kernel(const u16* __restrict__ ln,
                                   u16* __restrict__ out) {
  int idx = blockIdx.x * THREADS + threadIdx.x;
  if (idx >= 4096 * 2304) return;
  int col = idx % 2304, tok = idx / 2304;
  int n9 = col >> 8, c = col & 255;
  int y = tok >> 6, x = tok & 63;
  int yy = y + n9 / 3 - 1, xx = x + n9 % 3 - 1;
  out[idx] = (yy >= 0 && yy < 64 && xx >= 0 && xx < 64)
                 ? ln[((size_t)yy * 64 + xx) * 256 + c]
                 : (u16)0;
}

__global__ void ln2d_out_kernel(const float* __restrict__ in,
                                const float* __restrict__ w,
                                const float* __restrict__ b,
                                float* __restrict__ out) {
  __shared__ float red[4];
  int tok = blockIdx.x, t = threadIdx.x;
  float v = in[(size_t)tok * 256 + t];
  float s = block_reduce_sum256(v, red);
  float m = s / 256.f;
  float dv = v - m;
  float s2 = block_reduce_sum256(dv * dv, red);
  float inv = rsqrtf(s2 / 256.f + 1e-6f);
  out[(size_t)t * 4096 + tok] = dv * inv * w[t] + b[t];
}

// ---------------------------------------------------------------------------
extern "C" void kernel_launch(void* const* d_in, const int* in_sizes, int n_in,
                              void* d_out, int out_size, void* d_ws,
                              size_t ws_size, hipStream_t stream) {
  const float* pixel_values = (const float*)d_in[0];
  const float* patch_w = (const float*)d_in[1];
  const float* patch_b = (const float*)d_in[2];
  const float* pos_embed = (const float*)d_in[3];
  const float* ln1_w = (const float*)d_in[4];
  const float* ln1_b = (const float*)d_in[5];
  const float* qkv_w = (const float*)d_in[6];
  const float* qkv_b = (const float*)d_in[7];
  const float* proj_w = (const float*)d_in[8];
  const float* proj_b = (const float*)d_in[9];
  const float* rel_h0 = (const float*)d_in[10];
  const float* rel_w0 = (const float*)d_in[11];
  const float* rel_h1 = (const float*)d_in[12];
  const float* rel_w1 = (const float*)d_in[13];
  const float* ln2_w = (const float*)d_in[14];
  const float* ln2_b = (const float*)d_in[15];
  const float* mlp1_w = (const float*)d_in[16];
  const float* mlp1_b = (const float*)d_in[17];
  const float* mlp2_w = (const float*)d_in[18];
  const float* mlp2_b = (const float*)d_in[19];
  const float* neck1_w = (const float*)d_in[20];
  const float* nln1_w = (const float*)d_in[21];
  const float* nln1_b = (const float*)d_in[22];
  const float* neck2_w = (const float*)d_in[23];
  const float* nln2_w = (const float*)d_in[24];
  const float* nln2_b = (const float*)d_in[25];
  float* out = (float*)d_out;

  // ---- workspace layout (~110 MB) ----
  float* X = (float*)d_ws;                       // 3,145,728 f32
  u16* Xb = (u16*)(X + 3145728);                 // 3,145,728 u16
  float* H = (float*)(Xb + 3145728);             // 3,763,200 f32
  u16* Ab1 = (u16*)(H + 3763200);                // 3,763,200 u16
  u16* Ab2 = Ab1 + 3763200;                      // 12,582,912 u16
  u16* QKVb = Ab2 + 12582912;                    // 11,289,600 u16
  u16* RHb = QKVb + 11289600;                    // 3,145,728 u16
  u16* RWb = RHb + 3145728;                      // 3,145,728 u16
  u16* AOb = RWb + 3145728;                      // 3,763,200 u16
  u16* Wb = AOb + 3763200;                       // 589,824 u16 (neck2 weight)
  u16* LNb = Ab2 + 11520000;                     // 1,048,576 u16 (inside Ab2 tail)

  // ---- patch embed ----
  im2col_patch_kernel<<<12288, THREADS, 0, stream>>>(pixel_values, Ab2);
  gemm_bf16<0, 64, 1><<<dim3(12, 32), THREADS, 0, stream>>>(
      Ab2, patch_w, patch_b, pos_embed, X, nullptr, 4096, 768, 768);

  // ================= layer 0 (windowed, S=14, 25 windows) ==================
  ln_row_kernel<<<4096, THREADS, 0, stream>>>(X, ln1_w, ln1_b, Ab2, 768);
  win_part_kernel<<<14700, THREADS, 0, stream>>>(Ab2, Ab1);
  gemm_bf16<2, 128, 1><<<dim3(18, 39), THREADS, 0, stream>>>(
      Ab1, qkv_w, qkv_b, nullptr, QKVb, nullptr, 4900, 2304, 768);
  {
    int total = 25 * 12 * 14 * 14 * 14;
    relpos_kernel<<<(total + THREADS - 1) / THREADS, THREADS, 0, stream>>>(
        QKVb, rel_h0, rel_w0, RHb, RWb, 14, total);
  }
  attn_mfma_kernel<14><<<dim3(4, 300), THREADS, 29696, stream>>>(QKVb, RHb, RWb, AOb);
  gemm_bf16<0, 64, 1><<<dim3(12, 39), THREADS, 0, stream>>>(
      AOb, proj_w, proj_b, nullptr, H, nullptr, 4900, 768, 768);
  win_unpart_add_kernel<<<12288, THREADS, 0, stream>>>(H, X);
  // MLP 0
  ln_row_kernel<<<4096, THREADS, 0, stream>>>(X, ln2_w, ln2_b, Ab1, 768);
  gemm_bf16<1, 128, 1><<<dim3(24, 32), THREADS, 0, stream>>>(
      Ab1, mlp1_w, mlp1_b, nullptr, Ab2, nullptr, 4096, 3072, 768);
  gemm_bf16<0, 64, 1><<<dim3(12, 32), THREADS, 0, stream>>>(
      Ab2, mlp2_w, mlp2_b, X, X, nullptr, 4096, 768, 3072);

  // ================= layer 1 (global, S=64) ================================
  ln_row_kernel<<<4096, THREADS, 0, stream>>>(X, ln1_w + 768, ln1_b + 768, Ab1, 768);
  gemm_bf16<2, 128, 1><<<dim3(18, 32), THREADS, 0, stream>>>(
      Ab1, qkv_w + (size_t)2304 * 768, qkv_b + 2304, nullptr, QKVb, nullptr,
      4096, 2304, 768);
  relpos_mfma_kernel<0><<<768, THREADS, 0, stream>>>(QKVb, rel_h1, RHb);
  relpos_mfma_kernel<1><<<768, THREADS, 0, stream>>>(QKVb, rel_w1, RWb);
  attn_mfma_kernel<64><<<dim3(64, 12), THREADS, 32768, stream>>>(QKVb, RHb, RWb, AOb);
  gemm_bf16<0, 64, 1><<<dim3(12, 32), THREADS, 0, stream>>>(
      AOb, proj_w + (size_t)768 * 768, proj_b + 768, nullptr, H, nullptr,
      4096, 768, 768);
  add_kernel<<<12288, THREADS, 0, stream>>>(H, X, 4096 * 768);
  // MLP 1
  ln_row_kernel<<<4096, THREADS, 0, stream>>>(X, ln2_w + 768, ln2_b + 768, Ab1, 768);
  gemm_bf16<1, 128, 1><<<dim3(24, 32), THREADS, 0, stream>>>(
      Ab1, mlp1_w + (size_t)3072 * 768, mlp1_b + 3072, nullptr, Ab2, nullptr,
      4096, 3072, 768);
  gemm_bf16<3, 64, 1><<<dim3(12, 32), THREADS, 0, stream>>>(
      Ab2, mlp2_w + (size_t)768 * 3072, mlp2_b + 768, X, X, Xb,
      4096, 768, 3072);

  // ================= neck ==================================================
  gemm_bf16<0, 64, 1><<<dim3(4, 32), THREADS, 0, stream>>>(
      Xb, neck1_w, nullptr, nullptr, H, nullptr, 4096, 256, 768);
  ln_row_kernel<<<4096, THREADS, 0, stream>>>(H, nln1_w, nln1_b, LNb, 256);
  neck2w_kernel<<<2304, THREADS, 0, stream>>>(neck2_w, Wb);
  neck_im2col_kernel<<<36864, THREADS, 0, stream>>>(LNb, Ab2);
  gemm_bf16<0, 64, 0><<<dim3(4, 32), THREADS, 0, stream>>>(
      Ab2, Wb, nullptr, nullptr, H, nullptr, 4096, 256, 2304);
  ln2d_out_kernel<<<4096, THREADS, 0, stream>>>(H, nln2_w, nln2_b, out);
}

// Round 12
// 984.640 us; speedup vs baseline: 1.0457x; 1.0423x over previous
//
#include <hip/hip_runtime.h>
#include <hip/hip_bf16.h>
#include <cmath>
#include <cstddef>

#define THREADS 256
typedef unsigned short u16;
typedef unsigned int u32;
typedef __attribute__((ext_vector_type(8))) short bf16x8;
typedef __attribute__((ext_vector_type(4))) float f32x4;
#define MFMA16(a, b, c) __builtin_amdgcn_mfma_f32_16x16x32_bf16(a, b, c, 0, 0, 0)

__device__ __forceinline__ float bf2f(u16 u) {
  union { u32 i; float f; } x; x.i = ((u32)u) << 16; return x.f;
}
__device__ __forceinline__ u16 f2bf(float f) {
  __hip_bfloat16 h = __float2bfloat16(f);
  return *reinterpret_cast<u16*>(&h);
}
__device__ __forceinline__ u32 f2bf2(float a, float b) {
  __hip_bfloat162 h = __float22bfloat162_rn(make_float2(a, b));
  return *reinterpret_cast<u32*>(&h);
}
__device__ __forceinline__ uint4 cvt8(float4 x0, float4 x1) {
  return make_uint4(f2bf2(x0.x, x0.y), f2bf2(x0.z, x0.w),
                    f2bf2(x1.x, x1.y), f2bf2(x1.z, x1.w));
}

// async global->LDS, 16B per lane; LDS dest is wave-uniform base + lane*16
__device__ __forceinline__ void gload16(const u16* g, u16* l) {
  __builtin_amdgcn_global_load_lds(
      (const __attribute__((address_space(1))) unsigned int*)g,
      (__attribute__((address_space(3))) unsigned int*)l, 16, 0, 0);
}

__device__ __forceinline__ float block_reduce_sum256(float v, float* red4) {
  for (int off = 32; off > 0; off >>= 1) v += __shfl_down(v, off);
  __syncthreads();
  if ((threadIdx.x & 63) == 0) red4[threadIdx.x >> 6] = v;
  __syncthreads();
  return red4[0] + red4[1] + red4[2] + red4[3];
}

// ---------------------------------------------------------------------------
__global__ void f2b_kernel(const float* __restrict__ in, u16* __restrict__ out,
                           int n) {
  int i = (blockIdx.x * THREADS + threadIdx.x) * 4;
  if (i >= n) return;
  float4 v = *reinterpret_cast<const float4*>(in + i);
  ushort4 o;
  o.x = f2bf(v.x); o.y = f2bf(v.y); o.z = f2bf(v.z); o.w = f2bf(v.w);
  *reinterpret_cast<ushort4*>(out + i) = o;
}

// neck conv2 weight: src OIHW [256][256][3][3] -> dst [o][(ky*3+kx)*256 + c]
__global__ void neck2w_kernel(const float* __restrict__ src,
                              u16* __restrict__ dst) {
  int idx = blockIdx.x * THREADS + threadIdx.x;
  if (idx >= 256 * 2304) return;
  int o = idx / 2304, r = idx % 2304;
  int n9 = r >> 8, c = r & 255;
  dst[idx] = f2bf(src[(size_t)(o * 256 + c) * 9 + n9]);
}

// ---------------------------------------------------------------------------
__global__ void im2col_patch_kernel(const float* __restrict__ img,
                                    u16* __restrict__ out) {
  int idx = blockIdx.x * THREADS + threadIdx.x;
  if (idx >= 4096 * 768) return;
  int col = idx % 768, tok = idx / 768;
  int ph = tok / 64, pw = tok % 64;
  int c = col / 256, r = col % 256;
  int i = r / 16, j = r % 16;
  out[idx] = f2bf(img[(size_t)(c * 1024 + ph * 16 + i) * 1024 + pw * 16 + j]);
}

// ---------------------------------------------------------------------------
// MFMA GEMM: C[M,N] = A[M,K]bf16 @ B[N,K]bf16^T, fp32 accum.
// 128xBN tile (BN=128 or 64), BK=64, 4 waves. Staging via global_load_lds
// with source-side inverse XOR swizzle (slot c' holds chunk c'^(row&7)).
// MODE 0: f32 out (+bias)(+res); 1: GELU->bf16; 2: bf16, q-cols x0.125;
// MODE 3: f32 out + bf16 mirror out2.
// ---------------------------------------------------------------------------
template <int MODE, int BN>
__global__ __launch_bounds__(256)
void gemm_bf16(const u16* __restrict__ A, const u16* __restrict__ B,
               const float* __restrict__ bias, const float* __restrict__ res,
               void* __restrict__ out, void* __restrict__ out2,
               int M, int N, int K) {
  constexpr int NF = BN / 32;  // per-wave n fragments
  __shared__ __attribute__((aligned(16))) u16 As[128 * 64];
  __shared__ __attribute__((aligned(16))) u16 Bs[BN * 64];
  const int t = threadIdx.x;
  const int w = t >> 6, l = t & 63;
  const int m0 = blockIdx.y * 128, n0 = blockIdx.x * BN;
  const int wm = (w >> 1) * 64, wn = (w & 1) * (BN / 2);
  f32x4 acc[4][NF];
#pragma unroll
  for (int i = 0; i < 4; ++i)
#pragma unroll
    for (int j = 0; j < NF; ++j) acc[i][j] = (f32x4){0.f, 0.f, 0.f, 0.f};

  const int rr = l >> 3;                 // row-in-8 group
  const int cc = ((l & 7) ^ rr) * 8;     // source chunk offset (u16)
  const u16* aP[4];
  const u16* bP[NF];
#pragma unroll
  for (int j = 0; j < 4; ++j) {
    int ar = m0 + w * 32 + j * 8 + rr;
    if (ar >= M) ar = M - 1;
    aP[j] = A + (size_t)ar * K + cc;
  }
#pragma unroll
  for (int j = 0; j < NF; ++j)
    bP[j] = B + (size_t)(n0 + w * (BN / 4) + j * 8 + rr) * K + cc;
  u16* asw = &As[w * 2048];
  u16* bsw = &Bs[w * (BN * 16)];

  for (int k0 = 0; k0 < K; k0 += 64) {
    __syncthreads();
#pragma unroll
    for (int j = 0; j < 4; ++j) gload16(aP[j] + k0, asw + j * 512);
#pragma unroll
    for (int j = 0; j < NF; ++j) gload16(bP[j] + k0, bsw + j * 512);
    asm volatile("s_waitcnt vmcnt(0)" ::: "memory");
    __syncthreads();
#pragma unroll
    for (int kc = 0; kc < 2; ++kc) {
      bf16x8 af[4], bf[NF];
#pragma unroll
      for (int i = 0; i < 4; ++i) {
        int ar = wm + i * 16 + (l & 15);
        int ac = (kc * 4 + (l >> 4)) ^ (ar & 7);
        af[i] = *reinterpret_cast<const bf16x8*>(&As[ar * 64 + ac * 8]);
      }
#pragma unroll
      for (int j = 0; j < NF; ++j) {
        int br = wn + j * 16 + (l & 15);
        int bc = (kc * 4 + (l >> 4)) ^ (br & 7);
        bf[j] = *reinterpret_cast<const bf16x8*>(&Bs[br * 64 + bc * 8]);
      }
#pragma unroll
      for (int i = 0; i < 4; ++i)
#pragma unroll
        for (int j = 0; j < NF; ++j)
          acc[i][j] = MFMA16(af[i], bf[j], acc[i][j]);
    }
  }

#pragma unroll
  for (int i = 0; i < 4; ++i) {
#pragma unroll
    for (int reg = 0; reg < 4; ++reg) {
      int m = m0 + wm + i * 16 + (l >> 4) * 4 + reg;
      if (m >= M) continue;
#pragma unroll
      for (int j = 0; j < NF; ++j) {
        int n = n0 + wn + j * 16 + (l & 15);
        float v = acc[i][j][reg];
        if (bias) v += bias[n];
        if (MODE == 0 || MODE == 3) {
          if (res) v += res[(size_t)m * N + n];
          ((float*)out)[(size_t)m * N + n] = v;
          if (MODE == 3) ((u16*)out2)[(size_t)m * N + n] = f2bf(v);
        } else if (MODE == 1) {
          v = 0.5f * v * (1.0f + erff(v * 0.70710678118654752f));
          ((u16*)out)[(size_t)m * N + n] = f2bf(v);
        } else {  // MODE 2
          float sc = (n < 768) ? 0.125f : 1.0f;
          ((u16*)out)[(size_t)m * N + n] = f2bf(v * sc);
        }
      }
    }
  }
}

// ---------------------------------------------------------------------------
// relpos as batched 64x64x64 MFMA GEMM (S=64 only). Rtab f32, converted
// during LDS staging (table read once per block -> no amortization loss).
// ---------------------------------------------------------------------------
template <int WHICH>
__global__ __launch_bounds__(256)
void relpos_mfma_kernel(const u16* __restrict__ qkvb,
                        const float* __restrict__ Rtab,
                        u16* __restrict__ relout) {
  __shared__ __attribute__((aligned(16))) u16 Ql[64 * 64];
  __shared__ __attribute__((aligned(16))) u16 Rl[64 * 64];
  const int t = threadIdx.x, w = t >> 6, l = t & 63;
  const int head = blockIdx.x >> 6;
  const int fixed = blockIdx.x & 63;  // qh (WHICH=0) or qw (WHICH=1)
  const int rr = l >> 3;
  const int cc = ((l & 7) ^ rr) * 8;  // inverse-swizzled source chunk

#pragma unroll
  for (int j = 0; j < 2; ++j) {
    int row = w * 16 + j * 8 + rr;
    int tok = (WHICH == 0) ? (fixed * 64 + row) : (row * 64 + fixed);
    gload16(qkvb + (size_t)tok * 2304 + head * 64 + cc, &Ql[w * 1024 + j * 512]);
    int rrow = fixed - row + 63;  // always in [0,126]
    const float* rs = Rtab + (size_t)rrow * 64 + cc;
    float4 x0 = *reinterpret_cast<const float4*>(rs);
    float4 x1 = *reinterpret_cast<const float4*>(rs + 4);
    *reinterpret_cast<uint4*>(&Rl[w * 1024 + j * 512 + l * 8]) = cvt8(x0, x1);
  }
  asm volatile("s_waitcnt vmcnt(0)" ::: "memory");
  __syncthreads();

  f32x4 acc[4];
#pragma unroll
  for (int j = 0; j < 4; ++j) acc[j] = (f32x4){0.f, 0.f, 0.f, 0.f};
#pragma unroll
  for (int kc = 0; kc < 2; ++kc) {
    int ar = w * 16 + (l & 15);
    int ac = (kc * 4 + (l >> 4)) ^ (ar & 7);
    bf16x8 af = *reinterpret_cast<const bf16x8*>(&Ql[ar * 64 + ac * 8]);
#pragma unroll
    for (int j = 0; j < 4; ++j) {
      int br = j * 16 + (l & 15);
      int bc = (kc * 4 + (l >> 4)) ^ (br & 7);
      bf16x8 bf = *reinterpret_cast<const bf16x8*>(&Rl[br * 64 + bc * 8]);
      acc[j] = MFMA16(af, bf, acc[j]);
    }
  }

#pragma unroll
  for (int j = 0; j < 4; ++j) {
#pragma unroll
    for (int reg = 0; reg < 4; ++reg) {
      int m = w * 16 + (l >> 4) * 4 + reg;  // qw (WHICH=0) / qh (WHICH=1)
      int n = j * 16 + (l & 15);            // k
      size_t o = (WHICH == 0)
                     ? ((((size_t)head * 64 + fixed) * 64 + m) * 64 + n)
                     : ((((size_t)head * 64 + m) * 64 + fixed) * 64 + n);
      relout[o] = f2bf(acc[j][reg] * 8.0f);
    }
  }
}

// ---------------------------------------------------------------------------
__global__ void ln_row_kernel(const float* __restrict__ in,
                              const float* __restrict__ w,
                              const float* __restrict__ b,
                              u16* __restrict__ out, int D) {
  __shared__ float red[4];
  size_t base = (size_t)blockIdx.x * D;
  float s = 0.f, s2 = 0.f;
  for (int i = threadIdx.x; i < D; i += THREADS) {
    float v = in[base + i];
    s += v; s2 += v * v;
  }
  s = block_reduce_sum256(s, red);
  s2 = block_reduce_sum256(s2, red);
  float m = s / (float)D;
  float var = s2 / (float)D - m * m;
  float inv = rsqrtf(var + 1e-6f);
  for (int i = threadIdx.x; i < D; i += THREADS) {
    float v = in[base + i];
    out[base + i] = f2bf((v - m) * inv * w[i] + b[i]);
  }
}

// ---------------------------------------------------------------------------
__global__ void win_part_kernel(const u16* __restrict__ h,
                                u16* __restrict__ out) {
  int idx = blockIdx.x * THREADS + threadIdx.x;
  if (idx >= 4900 * 768) return;
  int c = idx % 768;
  int tok = idx / 768;
  int win = tok / 196, r = tok % 196;
  int wy = r / 14, wx = r % 14;
  int gy = (win / 5) * 14 + wy;
  int gx = (win % 5) * 14 + wx;
  out[idx] = (gy < 64 && gx < 64) ? h[((size_t)gy * 64 + gx) * 768 + c] : (u16)0;
}

__global__ void win_unpart_add_kernel(const float* __restrict__ p,
                                      float* __restrict__ x) {
  int idx = blockIdx.x * THREADS + threadIdx.x;
  if (idx >= 4096 * 768) return;
  int c = idx % 768;
  int tok = idx / 768;
  int gy = tok / 64, gx = tok % 64;
  int win = (gy / 14) * 5 + (gx / 14);
  int wy = gy % 14, wx = gx % 14;
  x[idx] += p[((size_t)(win * 196 + wy * 14 + wx)) * 768 + c];
}

__global__ void add_kernel(const float* __restrict__ p, float* __restrict__ x,
                           int n) {
  int idx = blockIdx.x * THREADS + threadIdx.x;
  if (idx < n) x[idx] += p[idx];
}

// ---------------------------------------------------------------------------
// scalar relpos (kept for S=14 windows only)
__global__ void relpos_kernel(const u16* __restrict__ qkvb,
                              const float* __restrict__ rh_tab,
                              const float* __restrict__ rw_tab,
                              u16* __restrict__ relh,
                              u16* __restrict__ relw,
                              int S, int total) {
  int idx = blockIdx.x * THREADS + threadIdx.x;
  if (idx >= total) return;
  int k = idx % S;
  int r = idx / S;
  int qw = r % S; r /= S;
  int qh = r % S; r /= S;
  int head = r % 12;
  int win = r / 12;
  int seq = S * S;
  int tok = win * seq + qh * S + qw;
  const u16* q = qkvb + (size_t)tok * 2304 + head * 64;
  const float* rh = rh_tab + (size_t)(qh - k + S - 1) * 64;
  const float* rw = rw_tab + (size_t)(qw - k + S - 1) * 64;
  float sh = 0.f, sw = 0.f;
#pragma unroll
  for (int d0 = 0; d0 < 64; d0 += 8) {
    uint4 qv = *reinterpret_cast<const uint4*>(q + d0);
    u16 qs[8];
    *reinterpret_cast<uint4*>(qs) = qv;
#pragma unroll
    for (int i = 0; i < 8; ++i) {
      float qq = bf2f(qs[i]);
      sh = fmaf(qq, rh[d0 + i], sh);
      sw = fmaf(qq, rw[d0 + i], sw);
    }
  }
  relh[idx] = f2bf(sh * 8.0f);
  relw[idx] = f2bf(sw * 8.0f);
}

// ---------------------------------------------------------------------------
// MFMA flash attention, swapped-QK^T form.
// S=64: TWO K-tiles per barrier phase — stage K/V for tiles t,t+1 into two
// LDS buffer sets, one vmcnt(0)+barrier, compute both. Halves stall events.
// LDS S=64: Kl0/Kl1 8K | Vt0/Vt1 8K | Pl 4K | RHl 4K u16 = 49152 B.
// S=14 single-buffer: 29696 B (proven).
// Vt swizzle: row d holds key at pos key ^ ((d&7)<<3).
// ---------------------------------------------------------------------------
template <int S>
__global__ __launch_bounds__(256)
void attn_mfma_kernel(const u16* __restrict__ qkvb,
                      const u16* __restrict__ RHt,
                      const u16* __restrict__ RWt,
                      u16* __restrict__ out) {
  constexpr int SEQ = S * S;
  constexpr int NKT = (SEQ + 63) / 64;
  constexpr bool TWO = (S == 64);
  constexpr int BIAS_N = (S == 14) ? 320 : 1024;
  extern __shared__ __attribute__((aligned(16))) u16 smem[];
  u16 *Kl0, *Kl1, *Vt0, *Vt1, *Plb, *RHlb, *RWlb = nullptr;
  if constexpr (TWO) {
    Kl0 = smem;          Kl1 = smem + 4096;
    Vt0 = smem + 8192;   Vt1 = smem + 12288;
    Plb = smem + 16384;
    RHlb = smem + 20480;
  } else {
    Kl0 = smem;          Kl1 = smem;
    Vt0 = smem + 4096;   Vt1 = smem + 4096;
    Plb = smem + 8192;
    RHlb = smem + 12288;
    RWlb = RHlb + 4 * BIAS_N;
  }

  const int t = threadIdx.x;
  const int w = t >> 6;
  const int l = t & 63;
  const int g = l >> 4;
  const int q = l & 15;
  const int bn = blockIdx.y;
  const int win = bn / 12, head = bn % 12;
  const int qbase = blockIdx.x * 64 + w * 16;
  const size_t tokbase = (size_t)win * SEQ;
  u16* Pl = Plb + w * 1024;
  u16* RHl = RHlb + w * BIAS_N;
  u16* RWl = RWlb + w * BIAS_N;

  {  // stage bias rows per wave, TRANSPOSED: [k_idx*16 + q_local]
    int ql = l >> 2;
    int qglob = qbase + ql;
    if (qglob > SEQ - 1) qglob = SEQ - 1;
    int qh = qglob / S, qw = qglob - qh * S;
    size_t bh = (((size_t)bn * S + qh) * S + qw) * S;
    for (int i = l & 3; i < S; i += 4) {
      RHl[i * 16 + ql] = RHt[bh + i];
      if constexpr (S == 14) RWl[i * 16 + ql] = RWt[bh + i];
    }
  }

  // S=64: rw bias is lane-resident (kw = sub*16 + g*4 + reg is lane-fixed)
  float rwreg[4][4];
  if constexpr (S == 64) {
    int qglob = qbase + q;
    size_t rwb = (((size_t)bn * 64 + (qglob >> 6)) * 64 + (qglob & 63)) * 64;
#pragma unroll
    for (int sub = 0; sub < 4; ++sub)
#pragma unroll
      for (int reg = 0; reg < 4; ++reg)
        rwreg[sub][reg] = bf2f(RWt[rwb + sub * 16 + g * 4 + reg]);
  }

  bf16x8 qf[2];
  {
    int qglob = qbase + q;
    if (qglob > SEQ - 1) qglob = SEQ - 1;
    const u16* qp = qkvb + (tokbase + qglob) * 2304 + head * 64 + g * 8;
    qf[0] = *reinterpret_cast<const bf16x8*>(qp);
    qf[1] = *reinterpret_cast<const bf16x8*>(qp + 32);
  }

  float m_run = -1e30f, l_run = 0.f;
  f32x4 Oacc[4];
#pragma unroll
  for (int dn = 0; dn < 4; ++dn) Oacc[dn] = (f32x4){0.f, 0.f, 0.f, 0.f};

  const int rr = l >> 3;
  const int kcc = ((l & 7) ^ rr) * 8;  // inverse-swizzled source chunk
  const int vkey = t & 63, vdg = t >> 6;

  auto stageK = [&](int kt, u16* Kd) {
#pragma unroll
    for (int j = 0; j < 2; ++j) {
      int kk = kt * 64 + w * 16 + j * 8 + rr;
      if (kk > SEQ - 1) kk = SEQ - 1;
      gload16(qkvb + (tokbase + kk) * 2304 + 768 + head * 64 + kcc,
              &Kd[w * 1024 + j * 512]);
    }
  };
  auto stageV = [&](int kt, u16* Vd) {
    int kk = kt * 64 + vkey;
    if (kk > SEQ - 1) kk = SEQ - 1;
    const uint4* src = reinterpret_cast<const uint4*>(
        qkvb + (tokbase + kk) * 2304 + 1536 + head * 64 + vdg * 16);
    uint4 a = src[0], b = src[1];
    u16 arr[16];
    *reinterpret_cast<uint4*>(&arr[0]) = a;
    *reinterpret_cast<uint4*>(&arr[8]) = b;
#pragma unroll
    for (int i = 0; i < 16; ++i)
      Vd[(vdg * 16 + i) * 64 + (vkey ^ ((i & 7) << 3))] = arr[i];
  };

  auto computeTile = [&](int kt, u16* Kl, u16* Vt) {
    const int k0 = kt * 64;
    f32x4 Sacc[4];
#pragma unroll
    for (int sub = 0; sub < 4; ++sub) {
      Sacc[sub] = (f32x4){0.f, 0.f, 0.f, 0.f};
#pragma unroll
      for (int kc = 0; kc < 2; ++kc) {
        int key = sub * 16 + q;
        int chunk = (kc * 4 + g) ^ (key & 7);
        bf16x8 kfr = *reinterpret_cast<const bf16x8*>(&Kl[key * 64 + (chunk << 3)]);
        Sacc[sub] = MFMA16(kfr, qf[kc], Sacc[sub]);  // swapped operands
      }
    }

    float sv[4][4];
    float tmax = -1e30f;
    if constexpr (S == 64) {
      float rhv = bf2f(RHl[kt * 16 + q]);
#pragma unroll
      for (int sub = 0; sub < 4; ++sub)
#pragma unroll
        for (int reg = 0; reg < 4; ++reg) {
          float s = Sacc[sub][reg] + rhv + rwreg[sub][reg];
          sv[sub][reg] = s;
          tmax = fmaxf(tmax, s);
        }
    } else {
#pragma unroll
      for (int sub = 0; sub < 4; ++sub)
#pragma unroll
        for (int reg = 0; reg < 4; ++reg) {
          int key = k0 + sub * 16 + g * 4 + reg;
          float s = -1e30f;
          if (key < SEQ) {
            int kh = key / S, kw = key - kh * S;
            s = Sacc[sub][reg] + bf2f(RHl[kh * 16 + q]) + bf2f(RWl[kw * 16 + q]);
          }
          sv[sub][reg] = s;
          tmax = fmaxf(tmax, s);
        }
    }
    tmax = fmaxf(tmax, __shfl_xor(tmax, 16));
    tmax = fmaxf(tmax, __shfl_xor(tmax, 32));

    if (!__all(tmax - m_run <= 8.0f)) {  // defer-max
      float mn = fmaxf(m_run, tmax);
      float sc = __expf(m_run - mn);
      l_run *= sc;
      m_run = mn;
#pragma unroll
      for (int reg = 0; reg < 4; ++reg) {
        float scq = __shfl(sc, g * 4 + reg);
#pragma unroll
        for (int dn = 0; dn < 4; ++dn) Oacc[dn][reg] *= scq;
      }
    }

    float psum = 0.f;
#pragma unroll
    for (int sub = 0; sub < 4; ++sub)
#pragma unroll
      for (int pr = 0; pr < 2; ++pr) {
        float p0 = __expf(sv[sub][2 * pr] - m_run);
        float p1 = __expf(sv[sub][2 * pr + 1] - m_run);
        psum += p0 + p1;
        u32 pk = f2bf2(p0, p1);
        int idx = (q * 64 + sub * 16 + g * 4 + pr * 2) ^ ((q & 7) << 3);
        *reinterpret_cast<u32*>(&Pl[idx]) = pk;
      }
    psum += __shfl_xor(psum, 16);
    psum += __shfl_xor(psum, 32);
    l_run += psum;

#pragma unroll
    for (int kc = 0; kc < 2; ++kc) {
      int chunk = (kc * 4 + g) ^ (q & 7);
      bf16x8 pa = *reinterpret_cast<const bf16x8*>(&Pl[q * 64 + (chunk << 3)]);
#pragma unroll
      for (int dn = 0; dn < 4; ++dn) {
        bf16x8 vb = *reinterpret_cast<const bf16x8*>(
            &Vt[(dn * 16 + q) * 64 + (chunk << 3)]);
        Oacc[dn] = MFMA16(pa, vb, Oacc[dn]);
      }
    }
  };

  if constexpr (TWO) {
    for (int kt = 0; kt < NKT; kt += 2) {
      __syncthreads();
      stageK(kt, Kl0);
      stageK(kt + 1, Kl1);
      stageV(kt, Vt0);
      stageV(kt + 1, Vt1);
      asm volatile("s_waitcnt vmcnt(0)" ::: "memory");
      __syncthreads();
      computeTile(kt, Kl0, Vt0);
      computeTile(kt + 1, Kl1, Vt1);
    }
  } else {
    for (int kt = 0; kt < NKT; ++kt) {
      __syncthreads();
      stageK(kt, Kl0);
      stageV(kt, Vt0);
      asm volatile("s_waitcnt vmcnt(0)" ::: "memory");
      __syncthreads();
      computeTile(kt, Kl0, Vt0);
    }
  }

  // ---- epilogue: O rows are queries g*4+reg; softmax state lives lane q
  float invq = 1.0f / l_run;
#pragma unroll
  for (int reg = 0; reg < 4; ++reg) {
    int ql = g * 4 + reg;
    int qglob = qbase + ql;
    if (qglob >= SEQ) continue;
    float inv = __shfl(invq, ql);
    u16* op = out + (tokbase + qglob) * 768 + head * 64;
#pragma unroll
    for (int dn = 0; dn < 4; ++dn)
      op[dn * 16 + q] = f2bf(Oacc[dn][reg] * inv);
  }
}

// ---------------------------------------------------------------------------
__global__ void neck_im2col_kernel(const u16* __restrict__ ln,
                                   u16* __restrict__ out) {
  int idx = blockIdx.x * THREADS + threadIdx.x;
  if (idx >= 4096 * 2304) return;
  int col = idx % 2304, tok = idx / 2304;
  int n9 = col >> 8, c = col & 255;
  int y = tok >> 6, x = tok & 63;
  int yy = y + n9 / 3 - 1, xx = x + n9 % 3 - 1;
  out[idx] = (yy >= 0 && yy < 64 && xx >= 0 && xx < 64)
                 ? ln[((size_t)yy * 64 + xx) * 256 + c]
                 : (u16)0;
}

__global__ void ln2d_out_kernel(const float* __restrict__ in,
                                const float* __restrict__ w,
                                const float* __restrict__ b,
                                float* __restrict__ out) {
  __shared__ float red[4];
  int tok = blockIdx.x, t = threadIdx.x;
  float v = in[(size_t)tok * 256 + t];
  float s = block_reduce_sum256(v, red);
  float m = s / 256.f;
  float dv = v - m;
  float s2 = block_reduce_sum256(dv * dv, red);
  float inv = rsqrtf(s2 / 256.f + 1e-6f);
  out[(size_t)t * 4096 + tok] = dv * inv * w[t] + b[t];
}

// ---------------------------------------------------------------------------
extern "C" void kernel_launch(void* const* d_in, const int* in_sizes, int n_in,
                              void* d_out, int out_size, void* d_ws,
                              size_t ws_size, hipStream_t stream) {
  const float* pixel_values = (const float*)d_in[0];
  const float* patch_w = (const float*)d_in[1];
  const float* patch_b = (const float*)d_in[2];
  const float* pos_embed = (const float*)d_in[3];
  const float* ln1_w = (const float*)d_in[4];
  const float* ln1_b = (const float*)d_in[5];
  const float* qkv_w = (const float*)d_in[6];
  const float* qkv_b = (const float*)d_in[7];
  const float* proj_w = (const float*)d_in[8];
  const float* proj_b = (const float*)d_in[9];
  const float* rel_h0 = (const float*)d_in[10];
  const float* rel_w0 = (const float*)d_in[11];
  const float* rel_h1 = (const float*)d_in[12];
  const float* rel_w1 = (const float*)d_in[13];
  const float* ln2_w = (const float*)d_in[14];
  const float* ln2_b = (const float*)d_in[15];
  const float* mlp1_w = (const float*)d_in[16];
  const float* mlp1_b = (const float*)d_in[17];
  const float* mlp2_w = (const float*)d_in[18];
  const float* mlp2_b = (const float*)d_in[19];
  const float* neck1_w = (const float*)d_in[20];
  const float* nln1_w = (const float*)d_in[21];
  const float* nln1_b = (const float*)d_in[22];
  const float* neck2_w = (const float*)d_in[23];
  const float* nln2_w = (const float*)d_in[24];
  const float* nln2_b = (const float*)d_in[25];
  float* out = (float*)d_out;

  // ---- workspace layout (~114 MB) ----
  float* X = (float*)d_ws;                       // 3,145,728 f32
  u16* Xb = (u16*)(X + 3145728);                 // 3,145,728 u16
  float* H = (float*)(Xb + 3145728);             // 3,763,200 f32
  u16* Ab1 = (u16*)(H + 3763200);                // 3,763,200 u16
  u16* Ab2 = Ab1 + 3763200;                      // 12,582,912 u16
  u16* QKVb = Ab2 + 12582912;                    // 11,289,600 u16
  u16* RHb = QKVb + 11289600;                    // 3,145,728 u16
  u16* RWb = RHb + 3145728;                      // 3,145,728 u16
  u16* AOb = RWb + 3145728;                      // 3,763,200 u16
  u16* Wb = AOb + 3763200;                       // 2,359,296 u16 (weight scratch)
  u16* LNb = Ab2 + 11520000;                     // 1,048,576 u16 (inside Ab2 tail)

#define CVT(src, n) f2b_kernel<<<((n) / 4 + THREADS - 1) / THREADS, THREADS, 0, stream>>>(src, Wb, n)

  // ---- patch embed ----
  im2col_patch_kernel<<<12288, THREADS, 0, stream>>>(pixel_values, Ab2);
  CVT(patch_w, 589824);
  gemm_bf16<0, 64><<<dim3(12, 32), THREADS, 0, stream>>>(
      Ab2, Wb, patch_b, pos_embed, X, nullptr, 4096, 768, 768);

  // ================= layer 0 (windowed, S=14, 25 windows) ==================
  ln_row_kernel<<<4096, THREADS, 0, stream>>>(X, ln1_w, ln1_b, Ab2, 768);
  win_part_kernel<<<14700, THREADS, 0, stream>>>(Ab2, Ab1);
  CVT(qkv_w, 1769472);
  gemm_bf16<2, 128><<<dim3(18, 39), THREADS, 0, stream>>>(
      Ab1, Wb, qkv_b, nullptr, QKVb, nullptr, 4900, 2304, 768);
  {
    int total = 25 * 12 * 14 * 14 * 14;
    relpos_kernel<<<(total + THREADS - 1) / THREADS, THREADS, 0, stream>>>(
        QKVb, rel_h0, rel_w0, RHb, RWb, 14, total);
  }
  attn_mfma_kernel<14><<<dim3(4, 300), THREADS, 29696, stream>>>(QKVb, RHb, RWb, AOb);
  CVT(proj_w, 589824);
  gemm_bf16<0, 64><<<dim3(12, 39), THREADS, 0, stream>>>(
      AOb, Wb, proj_b, nullptr, H, nullptr, 4900, 768, 768);
  win_unpart_add_kernel<<<12288, THREADS, 0, stream>>>(H, X);
  // MLP 0
  ln_row_kernel<<<4096, THREADS, 0, stream>>>(X, ln2_w, ln2_b, Ab1, 768);
  CVT(mlp1_w, 2359296);
  gemm_bf16<1, 128><<<dim3(24, 32), THREADS, 0, stream>>>(
      Ab1, Wb, mlp1_b, nullptr, Ab2, nullptr, 4096, 3072, 768);
  CVT(mlp2_w, 2359296);
  gemm_bf16<0, 64><<<dim3(12, 32), THREADS, 0, stream>>>(
      Ab2, Wb, mlp2_b, X, X, nullptr, 4096, 768, 3072);

  // ================= layer 1 (global, S=64) ================================
  ln_row_kernel<<<4096, THREADS, 0, stream>>>(X, ln1_w + 768, ln1_b + 768, Ab1, 768);
  CVT(qkv_w + (size_t)2304 * 768, 1769472);
  gemm_bf16<2, 128><<<dim3(18, 32), THREADS, 0, stream>>>(
      Ab1, Wb, qkv_b + 2304, nullptr, QKVb, nullptr, 4096, 2304, 768);
  relpos_mfma_kernel<0><<<768, THREADS, 0, stream>>>(QKVb, rel_h1, RHb);
  relpos_mfma_kernel<1><<<768, THREADS, 0, stream>>>(QKVb, rel_w1, RWb);
  attn_mfma_kernel<64><<<dim3(64, 12), THREADS, 49152, stream>>>(QKVb, RHb, RWb, AOb);
  CVT(proj_w + (size_t)768 * 768, 589824);
  gemm_bf16<0, 64><<<dim3(12, 32), THREADS, 0, stream>>>(
      AOb, Wb, proj_b + 768, nullptr, H, nullptr, 4096, 768, 768);
  add_kernel<<<12288, THREADS, 0, stream>>>(H, X, 4096 * 768);
  // MLP 1
  ln_row_kernel<<<4096, THREADS, 0, stream>>>(X, ln2_w + 768, ln2_b + 768, Ab1, 768);
  CVT(mlp1_w + (size_t)3072 * 768, 2359296);
  gemm_bf16<1, 128><<<dim3(24, 32), THREADS, 0, stream>>>(
      Ab1, Wb, mlp1_b + 3072, nullptr, Ab2, nullptr, 4096, 3072, 768);
  CVT(mlp2_w + (size_t)768 * 3072, 2359296);
  gemm_bf16<3, 64><<<dim3(12, 32), THREADS, 0, stream>>>(
      Ab2, Wb, mlp2_b + 768, X, X, Xb, 4096, 768, 3072);

  // ================= neck ==================================================
  CVT(neck1_w, 196608);
  gemm_bf16<0, 64><<<dim3(4, 32), THREADS, 0, stream>>>(
      Xb, Wb, nullptr, nullptr, H, nullptr, 4096, 256, 768);
  ln_row_kernel<<<4096, THREADS, 0, stream>>>(H, nln1_w, nln1_b, LNb, 256);
  neck2w_kernel<<<2304, THREADS, 0, stream>>>(neck2_w, Wb);
  neck_im2col_kernel<<<36864, THREADS, 0, stream>>>(LNb, Ab2);
  gemm_bf16<0, 64><<<dim3(4, 32), THREADS, 0, stream>>>(
      Ab2, Wb, nullptr, nullptr, H, nullptr, 4096, 256, 2304);
  ln2d_out_kernel<<<4096, THREADS, 0, stream>>>(H, nln2_w, nln2_b, out);
}